// Round 9
// baseline (1034.202 us; speedup 1.0000x reference)
//
#include <hip/hip_runtime.h>

#define NN 40000
#define NE 640000
#define F 128
#define NC 16
#define NT 32   // nodes per conv block

// ws layout (bytes); total exactly 23632384 == round-1 proven size
#define OFF_ROWPTR 0u          // (NN+1) ints
#define OFF_FILL   163968u     // NN ints
#define OFF_BSUM   327936u     // 64 ints
#define OFF_SORTED 328192u     // NE ints -> 2888192
#define OFF_STATS  2888192u    // 512 f32: [sum|bias2a][sumsq|biasExtra][bn_a][bn_b] (2048 B)
#define OFF_WT     2890240u    // 4x 128x128 f32 transposed: W1lT W1rT W2lT(BN-scaled) W2rT(BN-scaled)
#define OFF_XB     3152384u    // NN*F bf16 (x as bf16)      -> 13392384
#define OFF_H1     13392384u   // NN*F bf16 (h1)             -> 23632384

__device__ __forceinline__ unsigned short f2b(float f) {   // f32 -> bf16 RNE
    unsigned u = __builtin_bit_cast(unsigned, f);
    return (unsigned short)((u + 0x7fffu + ((u >> 16) & 1u)) >> 16);
}
__device__ __forceinline__ float b2f(unsigned short s) {
    return __builtin_bit_cast(float, (unsigned)s << 16);
}
__device__ __forceinline__ unsigned pk2(float lo, float hi) {
    return (unsigned)f2b(lo) | ((unsigned)f2b(hi) << 16);
}

__global__ __launch_bounds__(256) void k_hist(const int* __restrict__ ei, int* __restrict__ cnt) {
    int e = blockIdx.x * 256 + threadIdx.x;
    if (e < NE) atomicAdd(&cnt[ei[NE + e]], 1);
}

__global__ __launch_bounds__(1024) void k_scan1(const int* __restrict__ cnt, int* __restrict__ rowptr,
                                                int* __restrict__ bsum) {
    __shared__ int wsum[16];
    int t = threadIdx.x, b = blockIdx.x;
    int idx = b * 1024 + t;
    int v = (idx < NN) ? cnt[idx] : 0;
    int lane = t & 63, w = t >> 6;
    int val = v;
    #pragma unroll
    for (int off = 1; off < 64; off <<= 1) { int u = __shfl_up(val, off); if (lane >= off) val += u; }
    if (lane == 63) wsum[w] = val;
    __syncthreads();
    if (w == 0) {
        int x = (lane < 16) ? wsum[lane] : 0;
        #pragma unroll
        for (int off = 1; off < 16; off <<= 1) { int u = __shfl_up(x, off); if (lane >= off) x += u; }
        if (lane < 16) wsum[lane] = x;
    }
    __syncthreads();
    int excl = val - v + (w > 0 ? wsum[w - 1] : 0);
    if (idx < NN) rowptr[idx] = excl;
    if (t == 1023) bsum[b] = wsum[15];
}

__global__ __launch_bounds__(64) void k_scan2(int* __restrict__ bsum, int* __restrict__ rowptr) {
    int lane = threadIdx.x;
    int v = (lane < 40) ? bsum[lane] : 0;
    int val = v;
    #pragma unroll
    for (int off = 1; off < 64; off <<= 1) { int u = __shfl_up(val, off); if (lane >= off) val += u; }
    if (lane < 40) bsum[lane] = val - v;
    if (lane == 0) rowptr[NN] = NE;
}

__global__ __launch_bounds__(1024) void k_scan3(int* __restrict__ rowptr, const int* __restrict__ bsum,
                                                int* __restrict__ fill) {
    int t = threadIdx.x, b = blockIdx.x;
    int idx = b * 1024 + t;
    if (idx < NN) {
        int r = rowptr[idx] + bsum[b];
        rowptr[idx] = r;
        fill[idx] = r;
    }
}

__global__ __launch_bounds__(256) void k_scatter(const int* __restrict__ ei, int* __restrict__ fill,
                                                 int* __restrict__ sorted) {
    int e = blockIdx.x * 256 + threadIdx.x;
    if (e < NE) {
        int src = ei[e], dst = ei[NE + e];
        int pos = atomicAdd(&fill[dst], 1);
        sorted[pos] = src;
    }
}

// transpose W1l, W1r to f32 [k][out]
__global__ __launch_bounds__(256) void k_transpose(const float* __restrict__ W1l, const float* __restrict__ W1r,
                                                   float* __restrict__ WT) {
    int i = blockIdx.x * 256 + threadIdx.x;      // < 2*16384
    int m = i >> 14, rc = i & 16383, r = rc >> 7, c = rc & 127;
    const float* src = (m == 0) ? W1l : W1r;
    WT[m * 16384 + c * 128 + r] = src[rc];
}

// x (f32) -> xb (bf16), 8 elems/thread, coalesced
__global__ __launch_bounds__(256) void k_x2b(const float* __restrict__ x, unsigned short* __restrict__ xb) {
    int i = (blockIdx.x * 256 + threadIdx.x) * 8;
    float4 lo = *(const float4*)&x[i];
    float4 hi = *(const float4*)&x[i + 4];
    uint4 o;
    o.x = pk2(lo.x, lo.y); o.y = pk2(lo.z, lo.w);
    o.z = pk2(hi.x, hi.y); o.w = pk2(hi.z, hi.w);
    *(uint4*)&xb[i] = o;
}

__global__ __launch_bounds__(128) void k_bnfinal(float* __restrict__ stats, const float* __restrict__ gamma,
                                                 const float* __restrict__ beta) {
    int t = threadIdx.x;
    float mu  = stats[t] * (1.f / NN);
    float var = stats[F + t] * (1.f / NN) - mu * mu;
    float a = gamma[t] * rsqrtf(var + 1e-5f);
    stats[256 + t] = a;
    stats[384 + t] = beta[t] - mu * a;
}

// Fold BN affine into conv2: emit f32 TRANSPOSED scaled weights + bias vectors.
// stats[128..255] := biasExtra = b_bn @ W2l.T (applied iff deg>0)
// stats[0..127]   := bias2a   = b2l + b_bn @ W2r.T (always)
// (sum/sumsq slots are dead after k_bnfinal — safe reuse.)
__global__ __launch_bounds__(256) void k_wprep2(const float* __restrict__ W2l, const float* __restrict__ W2r,
                                                const float* __restrict__ b2l, float* __restrict__ stats,
                                                float* __restrict__ w2lT, float* __restrict__ w2rT) {
    int t = threadIdx.x;
    int o = t & 127;
    bool isL = t < 128;
    const float* W = isL ? W2l : W2r;
    float* WT = isL ? w2lT : w2rT;
    float dot = 0.f;
    for (int k = 0; k < F; ++k) {
        float w = W[o * F + k];
        WT[k * F + o] = w * stats[256 + k];      // coalesced per-k store
        dot = fmaf(stats[384 + k], w, dot);
    }
    if (isL) stats[128 + o] = dot;
    else     stats[o] = b2l[o] + dot;
}

#define FMA4(AR, W, S) \
    AR[0] = fmaf((W).x, (S), AR[0]); \
    AR[1] = fmaf((W).y, (S), AR[1]); \
    AR[2] = fmaf((W).z, (S), AR[2]); \
    AR[3] = fmaf((W).w, (S), AR[3]);

#define KSTEP(CUR) \
    { \
        _Pragma("unroll") \
        for (int ni = 0; ni < 4; ++ni) { \
            float4 av = *(const float4*)&sA[tn + ni][k]; \
            float4 xv = *(const float4*)&sX[tn + ni][k]; \
            float* ar = acc[ni]; \
            FMA4(ar, wl[CUR][0], av.x) FMA4(ar, wl[CUR][1], av.y) \
            FMA4(ar, wl[CUR][2], av.z) FMA4(ar, wl[CUR][3], av.w) \
            FMA4(ar, wr[CUR][0], xv.x) FMA4(ar, wr[CUR][1], xv.y) \
            FMA4(ar, wr[CUR][2], xv.z) FMA4(ar, wr[CUR][3], xv.w) \
        } \
    }

#define WLOAD(BUF, KK) \
    { \
        _Pragma("unroll") \
        for (int j = 0; j < 4; ++j) { \
            wl[BUF][j] = *(const float4*)&WlT[(KK + j) * F + to]; \
            wr[BUF][j] = *(const float4*)&WrT[(KK + j) * F + to]; \
        } \
    }

// Fused conv: block-local edge-parallel gather (LDS f32 atomics) + r4-proven VALU dual GEMM
// + bias + row-L2-norm + epilogue (conv1: relu+h1+BN stats; conv2: fc->out).
// Kills the aggm cross-kernel/cross-XCD HBM round-trip that pinned k_gemm at ~100us (r6-r8).
template<int CONV2>
__global__ __launch_bounds__(256) void k_conv(
    const unsigned short* __restrict__ featb,    // conv1: xb, conv2: h1 (gather AND self source)
    const int* __restrict__ rowptr, const int* __restrict__ sorted,
    const float* __restrict__ WlT, const float* __restrict__ WrT,
    const float* __restrict__ bias1,             // conv1: b1l
    const float* __restrict__ biasA, const float* __restrict__ biasE,  // conv2
    unsigned short* __restrict__ h1, float* __restrict__ stats,
    const float* __restrict__ Wfc, const float* __restrict__ bfc,
    float* __restrict__ out)
{
    __shared__ float sA[NT][F];     // gathered neighbor sums -> means
    __shared__ float sX[NT][F];     // self rows (f32 from bf16)
    __shared__ float sScale[NT];
    __shared__ int sRp[NT + 1];
    int t = threadIdx.x;
    int nb = blockIdx.x * NT;

    if (t < NT + 1) sRp[t] = rowptr[nb + t];
    {   // zero sA (4096 f32), stage sX (4096 bf16 -> f32), all coalesced
        float* z = &sA[0][0];
        #pragma unroll
        for (int i = 0; i < 16; ++i) z[t + i * 256] = 0.f;
        const uint4* src = (const uint4*)(featb + (size_t)nb * F);
        float* dst = &sX[0][0];
        #pragma unroll
        for (int i = 0; i < 2; ++i) {
            uint4 u = src[t + i * 256];
            int base = (t + i * 256) * 8;
            float4 lo, hi;
            lo.x = b2f((unsigned short)(u.x & 0xffff)); lo.y = b2f((unsigned short)(u.x >> 16));
            lo.z = b2f((unsigned short)(u.y & 0xffff)); lo.w = b2f((unsigned short)(u.y >> 16));
            hi.x = b2f((unsigned short)(u.z & 0xffff)); hi.y = b2f((unsigned short)(u.z >> 16));
            hi.z = b2f((unsigned short)(u.w & 0xffff)); hi.w = b2f((unsigned short)(u.w >> 16));
            *(float4*)&dst[base] = lo;
            *(float4*)&dst[base + 4] = hi;
        }
    }
    __syncthreads();

    // ---- edge-parallel gather: 16 groups x 16 lanes; dst via 5-step binary search ----
    {
        int e0 = sRp[0], e1 = sRp[NT];
        int g = t >> 4, li = t & 15;
        for (int e = e0 + g; e < e1; e += 16) {
            int s = sorted[e];
            int lo = 0, hi = NT;
            #pragma unroll
            for (int it = 0; it < 5; ++it) {
                int mid = (lo + hi) >> 1;
                if (e >= sRp[mid]) lo = mid; else hi = mid;
            }
            uint4 u = *(const uint4*)(featb + (size_t)s * F + li * 8);
            float* row = &sA[lo][li * 8];
            atomicAdd(row + 0, b2f((unsigned short)(u.x & 0xffff)));
            atomicAdd(row + 1, b2f((unsigned short)(u.x >> 16)));
            atomicAdd(row + 2, b2f((unsigned short)(u.y & 0xffff)));
            atomicAdd(row + 3, b2f((unsigned short)(u.y >> 16)));
            atomicAdd(row + 4, b2f((unsigned short)(u.z & 0xffff)));
            atomicAdd(row + 5, b2f((unsigned short)(u.z >> 16)));
            atomicAdd(row + 6, b2f((unsigned short)(u.w & 0xffff)));
            atomicAdd(row + 7, b2f((unsigned short)(u.w >> 16)));
        }
    }
    __syncthreads();

    // ---- mean ----
    {
        int n = t >> 3, c0 = (t & 7) * 16;
        int deg = sRp[n + 1] - sRp[n];
        float inv = 1.f / (float)(deg > 1 ? deg : 1);
        #pragma unroll
        for (int j = 0; j < 16; ++j) sA[n][c0 + j] *= inv;
    }
    __syncthreads();

    // ---- dual GEMM (r4-proven): thread = 4 nodes x 4 outs, 2-deep weight reg dbuf ----
    int tn = (t >> 5) << 2;
    int to = (t & 31) << 2;
    float acc[4][4];
    #pragma unroll
    for (int i = 0; i < 4; ++i)
        #pragma unroll
        for (int j = 0; j < 4; ++j) acc[i][j] = 0.f;

    float4 wl[2][4], wr[2][4];
    WLOAD(0, 0)
    for (int k = 0; k < F - 8; k += 8) {
        WLOAD(1, (k + 4))
        KSTEP(0)
        k += 4;
        WLOAD(0, (k + 4))
        KSTEP(1)
        k -= 4;
    }
    {
        int k = F - 8;
        WLOAD(1, (k + 4))
        KSTEP(0)
        k += 4;
        KSTEP(1)
    }

    // ---- bias + row L2 norm ----
    if constexpr (!CONV2) {
        float4 bv = *(const float4*)&bias1[to];
        #pragma unroll
        for (int ni = 0; ni < 4; ++ni) {
            acc[ni][0] += bv.x; acc[ni][1] += bv.y; acc[ni][2] += bv.z; acc[ni][3] += bv.w;
        }
    } else {
        float4 ba = *(const float4*)&biasA[to];
        float4 be = *(const float4*)&biasE[to];
        #pragma unroll
        for (int ni = 0; ni < 4; ++ni) {
            float flg = (sRp[tn + ni + 1] > sRp[tn + ni]) ? 1.f : 0.f;
            acc[ni][0] += ba.x + flg * be.x;
            acc[ni][1] += ba.y + flg * be.y;
            acc[ni][2] += ba.z + flg * be.z;
            acc[ni][3] += ba.w + flg * be.w;
        }
    }
    #pragma unroll
    for (int ni = 0; ni < 4; ++ni) {
        float s = acc[ni][0] * acc[ni][0] + acc[ni][1] * acc[ni][1]
                + acc[ni][2] * acc[ni][2] + acc[ni][3] * acc[ni][3];
        #pragma unroll
        for (int off = 1; off <= 16; off <<= 1) s += __shfl_xor(s, off);
        if ((t & 31) == 0) sScale[tn + ni] = 1.f / fmaxf(sqrtf(s), 1e-12f);
    }
    __syncthreads();   // k-loop LDS reads done in all waves; sScale visible

    if constexpr (!CONV2) {
        // normalize + relu -> sA (f32, BN stats) + h1 (bf16)
        #pragma unroll
        for (int ni = 0; ni < 4; ++ni) {
            float sc = sScale[tn + ni];
            float4 v;
            v.x = fmaxf(acc[ni][0] * sc, 0.f);
            v.y = fmaxf(acc[ni][1] * sc, 0.f);
            v.z = fmaxf(acc[ni][2] * sc, 0.f);
            v.w = fmaxf(acc[ni][3] * sc, 0.f);
            *(float4*)&sA[tn + ni][to] = v;
            uint2 p; p.x = pk2(v.x, v.y); p.y = pk2(v.z, v.w);
            *(uint2*)&h1[(size_t)(nb + tn + ni) * F + to] = p;
        }
        __syncthreads();
        if (t < F) {
            float s = 0.f, s2 = 0.f;
            #pragma unroll
            for (int r = 0; r < NT; ++r) {
                float h = sA[r][t];
                s += h; s2 = fmaf(h, h, s2);
            }
            atomicAdd(&stats[t], s);
            atomicAdd(&stats[F + t], s2);
        }
    } else {
        #pragma unroll
        for (int ni = 0; ni < 4; ++ni) {
            float sc = sScale[tn + ni];
            float4 v;
            v.x = acc[ni][0] * sc; v.y = acc[ni][1] * sc;
            v.z = acc[ni][2] * sc; v.w = acc[ni][3] * sc;
            *(float4*)&sA[tn + ni][to] = v;
        }
        __syncthreads();
        for (int p = t; p < NT * NC; p += 256) {
            int n = p >> 4, c = p & 15;
            float s = bfc[c];
            for (int o = 0; o < F; o += 4) {
                float4 h4 = *(const float4*)&sA[n][o];
                float4 w4 = *(const float4*)&Wfc[c * F + o];
                s += h4.x * w4.x + h4.y * w4.y + h4.z * w4.z + h4.w * w4.w;
            }
            out[(size_t)(nb + n) * NC + c] = s;
        }
    }
}

extern "C" void kernel_launch(void* const* d_in, const int* in_sizes, int n_in,
                              void* d_out, int out_size, void* d_ws, size_t ws_size,
                              hipStream_t stream) {
    const float* x     = (const float*)d_in[0];
    const int*   ei    = (const int*)d_in[1];
    const float* W1l   = (const float*)d_in[2];
    const float* b1l   = (const float*)d_in[3];
    const float* W1r   = (const float*)d_in[4];
    const float* gamma = (const float*)d_in[5];
    const float* beta  = (const float*)d_in[6];
    const float* W2l   = (const float*)d_in[7];
    const float* b2l   = (const float*)d_in[8];
    const float* W2r   = (const float*)d_in[9];
    const float* Wfc   = (const float*)d_in[10];
    const float* bfc   = (const float*)d_in[11];

    char* ws = (char*)d_ws;
    int*            rowptr = (int*)(ws + OFF_ROWPTR);
    int*            fill   = (int*)(ws + OFF_FILL);
    int*            bsum   = (int*)(ws + OFF_BSUM);
    int*            sorted = (int*)(ws + OFF_SORTED);
    float*          stats  = (float*)(ws + OFF_STATS);
    float*          WT     = (float*)(ws + OFF_WT);
    unsigned short* xb     = (unsigned short*)(ws + OFF_XB);
    unsigned short* h1     = (unsigned short*)(ws + OFF_H1);
    float*          out    = (float*)d_out;

    hipMemsetAsync(fill, 0, NN * sizeof(int), stream);
    hipMemsetAsync(stats, 0, 256 * sizeof(float), stream);

    k_transpose<<<128, 256, 0, stream>>>(W1l, W1r, WT);
    k_x2b<<<NN * F / (256 * 8), 256, 0, stream>>>(x, xb);
    k_hist<<<(NE + 255) / 256, 256, 0, stream>>>(ei, fill);
    k_scan1<<<40, 1024, 0, stream>>>(fill, rowptr, bsum);
    k_scan2<<<1, 64, 0, stream>>>(bsum, rowptr);
    k_scan3<<<40, 1024, 0, stream>>>(rowptr, bsum, fill);
    k_scatter<<<(NE + 255) / 256, 256, 0, stream>>>(ei, fill, sorted);

    // conv1: fused gather + GEMM + L2norm + ReLU -> h1, BN partial stats
    k_conv<0><<<NN / NT, 256, 0, stream>>>(xb, rowptr, sorted, WT, WT + 16384, b1l,
                                           nullptr, nullptr, h1, stats,
                                           nullptr, nullptr, nullptr);
    k_bnfinal<<<1, 128, 0, stream>>>(stats, gamma, beta);
    k_wprep2<<<1, 256, 0, stream>>>(W2l, W2r, b2l, stats, WT + 32768, WT + 49152);

    // conv2: fused gather + GEMM + L2norm + fc -> out
    k_conv<1><<<NN / NT, 256, 0, stream>>>(h1, rowptr, sorted, WT + 32768, WT + 49152, nullptr,
                                           stats, stats + 128, nullptr, nullptr,
                                           Wfc, bfc, out);
}

// Round 10
// 337.619 us; speedup vs baseline: 3.0632x; 3.0632x over previous
//
#include <hip/hip_runtime.h>

#define NN 40000
#define NE 640000
#define F 128
#define NC 16
#define NT 64   // nodes per gemm block

// ws layout (bytes); total 23501312 < proven 23632384
#define OFF_ROWPTR 0u          // (NN+1) ints
#define OFF_FILL   163968u     // NN ints
#define OFF_BSUM   327936u     // 64 ints
#define OFF_SORTED 328192u     // NE ints -> 2888192
#define OFF_STATS  2888192u    // 512 f32: [sum|bias2a][sumsq|biasExtra][bn_a][bn_b] (2048 B)
#define OFF_W1T    2890240u    // w1lT | w1rT bf16 [k][out] (64 KB)
#define OFF_W2T    2955776u    // w2lT | w2rT bf16 [k][out], BN-scaled (64 KB)
#define OFF_XB     3021312u    // NN*F bf16: xb, then h1 overwrites same rows (block-exclusive)
#define OFF_AGGM   13261312u   // NN*F bf16 -> 23501312

__device__ __forceinline__ unsigned short f2b(float f) {   // f32 -> bf16 RNE
    unsigned u = __builtin_bit_cast(unsigned, f);
    return (unsigned short)((u + 0x7fffu + ((u >> 16) & 1u)) >> 16);
}
__device__ __forceinline__ float b2f(unsigned short s) {
    return __builtin_bit_cast(float, (unsigned)s << 16);
}
__device__ __forceinline__ unsigned pk2(float lo, float hi) {
    return (unsigned)f2b(lo) | ((unsigned)f2b(hi) << 16);
}
__device__ __forceinline__ float blo(unsigned u) { return __builtin_bit_cast(float, u << 16); }
__device__ __forceinline__ float bhi(unsigned u) { return __builtin_bit_cast(float, u & 0xffff0000u); }

__global__ __launch_bounds__(256) void k_hist(const int* __restrict__ ei, int* __restrict__ cnt) {
    int e = blockIdx.x * 256 + threadIdx.x;
    if (e < NE) atomicAdd(&cnt[ei[NE + e]], 1);
}

__global__ __launch_bounds__(1024) void k_scan1(const int* __restrict__ cnt, int* __restrict__ rowptr,
                                                int* __restrict__ bsum) {
    __shared__ int wsum[16];
    int t = threadIdx.x, b = blockIdx.x;
    int idx = b * 1024 + t;
    int v = (idx < NN) ? cnt[idx] : 0;
    int lane = t & 63, w = t >> 6;
    int val = v;
    #pragma unroll
    for (int off = 1; off < 64; off <<= 1) { int u = __shfl_up(val, off); if (lane >= off) val += u; }
    if (lane == 63) wsum[w] = val;
    __syncthreads();
    if (w == 0) {
        int x = (lane < 16) ? wsum[lane] : 0;
        #pragma unroll
        for (int off = 1; off < 16; off <<= 1) { int u = __shfl_up(x, off); if (lane >= off) x += u; }
        if (lane < 16) wsum[lane] = x;
    }
    __syncthreads();
    int excl = val - v + (w > 0 ? wsum[w - 1] : 0);
    if (idx < NN) rowptr[idx] = excl;
    if (t == 1023) bsum[b] = wsum[15];
}

__global__ __launch_bounds__(64) void k_scan2(int* __restrict__ bsum, int* __restrict__ rowptr) {
    int lane = threadIdx.x;
    int v = (lane < 40) ? bsum[lane] : 0;
    int val = v;
    #pragma unroll
    for (int off = 1; off < 64; off <<= 1) { int u = __shfl_up(val, off); if (lane >= off) val += u; }
    if (lane < 40) bsum[lane] = val - v;
    if (lane == 0) rowptr[NN] = NE;
}

__global__ __launch_bounds__(1024) void k_scan3(int* __restrict__ rowptr, const int* __restrict__ bsum,
                                                int* __restrict__ fill) {
    int t = threadIdx.x, b = blockIdx.x;
    int idx = b * 1024 + t;
    if (idx < NN) {
        int r = rowptr[idx] + bsum[b];
        rowptr[idx] = r;
        fill[idx] = r;
    }
}

__global__ __launch_bounds__(256) void k_scatter(const int* __restrict__ ei, int* __restrict__ fill,
                                                 int* __restrict__ sorted) {
    int e = blockIdx.x * 256 + threadIdx.x;
    if (e < NE) {
        int src = ei[e], dst = ei[NE + e];
        int pos = atomicAdd(&fill[dst], 1);
        sorted[pos] = src;
    }
}

// W1l,W1r f32 [o][k] -> bf16 transposed [k][o]
__global__ __launch_bounds__(256) void k_wprep1(const float* __restrict__ W1l, const float* __restrict__ W1r,
                                                unsigned short* __restrict__ w1T) {
    int i = blockIdx.x * 256 + threadIdx.x;      // < 32768
    int m = i >> 14, rc = i & 16383, o = rc >> 7, k = rc & 127;
    const float* src = (m == 0) ? W1l : W1r;
    w1T[m * 16384 + k * 128 + o] = f2b(src[rc]);
}

// x (f32) -> xb (bf16), 8 elems/thread, coalesced
__global__ __launch_bounds__(256) void k_x2b(const float* __restrict__ x, unsigned short* __restrict__ xb) {
    int i = (blockIdx.x * 256 + threadIdx.x) * 8;
    float4 lo = *(const float4*)&x[i];
    float4 hi = *(const float4*)&x[i + 4];
    uint4 o;
    o.x = pk2(lo.x, lo.y); o.y = pk2(lo.z, lo.w);
    o.z = pk2(hi.x, hi.y); o.w = pk2(hi.z, hi.w);
    *(uint4*)&xb[i] = o;
}

__global__ __launch_bounds__(128) void k_bnfinal(float* __restrict__ stats, const float* __restrict__ gamma,
                                                 const float* __restrict__ beta) {
    int t = threadIdx.x;
    float mu  = stats[t] * (1.f / NN);
    float var = stats[F + t] * (1.f / NN) - mu * mu;
    float a = gamma[t] * rsqrtf(var + 1e-5f);
    stats[256 + t] = a;
    stats[384 + t] = beta[t] - mu * a;
}

// Fold BN into conv2 weights (bf16, transposed, scaled) + bias vectors in stats[0..255].
__global__ __launch_bounds__(256) void k_wprep2(const float* __restrict__ W2l, const float* __restrict__ W2r,
                                                const float* __restrict__ b2l, float* __restrict__ stats,
                                                unsigned short* __restrict__ w2T) {
    int t = threadIdx.x;
    int o = t & 127;
    bool isL = t < 128;
    const float* W = isL ? W2l : W2r;
    unsigned short* dst = w2T + (isL ? 0 : 16384);
    float dot = 0.f;
    for (int k = 0; k < F; ++k) {
        float w = W[o * F + k];
        dst[k * 128 + o] = f2b(w * stats[256 + k]);
        dot = fmaf(stats[384 + k], w, dot);
    }
    if (isL) stats[128 + o] = dot;       // biasExtra (iff deg>0)
    else     stats[o] = b2l[o] + dot;    // bias2a (always)
}

// Gather (neighbor mean): one wave per node; quarter q, 4 rows in flight per lane (16 edges/iter).
__global__ __launch_bounds__(256) void k_agg(
    const unsigned short* __restrict__ featb,
    const int* __restrict__ rowptr, const int* __restrict__ sorted,
    unsigned short* __restrict__ aggm)
{
    int node = (blockIdx.x << 2) + (threadIdx.x >> 6);
    int lane = threadIdx.x & 63;
    int q = lane >> 4, li = lane & 15;
    int fo = li << 3;
    int e0 = rowptr[node], e1 = rowptr[node + 1];
    int deg = e1 - e0;
    float a0=0.f,a1=0.f,a2=0.f,a3=0.f,a4=0.f,a5=0.f,a6=0.f,a7=0.f;

#define ACC_EDGE(SRC) do { \
        uint4 u = *(const uint4*)&featb[(size_t)(SRC) * F + fo]; \
        a0 += blo(u.x); a1 += bhi(u.x); \
        a2 += blo(u.y); a3 += bhi(u.y); \
        a4 += blo(u.z); a5 += bhi(u.z); \
        a6 += blo(u.w); a7 += bhi(u.w); \
    } while (0)

    int e = e0;
    for (; e + 16 <= e1; e += 16) {
        int s0 = sorted[e + q];
        int s1 = sorted[e + 4 + q];
        int s2 = sorted[e + 8 + q];
        int s3 = sorted[e + 12 + q];
        ACC_EDGE(s0); ACC_EDGE(s1); ACC_EDGE(s2); ACC_EDGE(s3);
    }
    for (; e + 4 <= e1; e += 4) {
        int s0 = sorted[e + q];
        ACC_EDGE(s0);
    }
    if (e < e1 && q < (e1 - e)) {
        int s0 = sorted[e + q];
        ACC_EDGE(s0);
    }
#undef ACC_EDGE

    #pragma unroll
    for (int m = 16; m <= 32; m <<= 1) {
        a0 += __shfl_xor(a0, m); a1 += __shfl_xor(a1, m);
        a2 += __shfl_xor(a2, m); a3 += __shfl_xor(a3, m);
        a4 += __shfl_xor(a4, m); a5 += __shfl_xor(a5, m);
        a6 += __shfl_xor(a6, m); a7 += __shfl_xor(a7, m);
    }

    if (q == 0) {
        float inv = 1.f / (float)(deg > 1 ? deg : 1);
        uint4 o;
        o.x = pk2(a0 * inv, a1 * inv);
        o.y = pk2(a2 * inv, a3 * inv);
        o.z = pk2(a4 * inv, a5 * inv);
        o.w = pk2(a6 * inv, a7 * inv);
        *(uint4*)&aggm[(size_t)node * F + fo] = o;
    }
}

// Note: bhi gives the bf16 value directly; unpack costs 1 VALU op per float.
// Dual GEMM (VALU, L2-BW-optimized): 64 nodes/block, thread = 8 nodes x 4 outs.
// bf16 weights [k][out] with 2-deep reg dbuf (halves L2 bytes vs r4); bf16 LDS tiles
// (staging = raw uint4 copies; k-loop ds_read_b64 is wave-broadcast -> conflict-free).
// Weight L2 traffic: 2KB/thread -> 320 MB/conv (r4: 1.25 GB @ 16.7 TB/s = its 75us wall).
#define UP4(VF, U2) { VF.x = blo((U2).x); VF.y = bhi((U2).x); VF.z = blo((U2).y); VF.w = bhi((U2).y); }

#define WLOAD(B, KK) { \
    _Pragma("unroll") \
    for (int j = 0; j < 4; ++j) { \
        wlr[B][j] = *(const uint2*)&WlT[(KK + j) * F + og4]; \
        wrr[B][j] = *(const uint2*)&WrT[(KK + j) * F + og4]; \
    } }

#define KSTEP(B, KK) { \
    float4 wlf[4], wrf[4]; \
    _Pragma("unroll") \
    for (int j = 0; j < 4; ++j) { UP4(wlf[j], wlr[B][j]) UP4(wrf[j], wrr[B][j]) } \
    _Pragma("unroll") \
    for (int ni = 0; ni < 8; ++ni) { \
        int row = ng8 + ni; \
        uint2 ua = *(const uint2*)(smem + row * 256 + (KK) * 2); \
        uint2 ux = *(const uint2*)(smem + 16384 + row * 256 + (KK) * 2); \
        float av[4] = { blo(ua.x), bhi(ua.x), blo(ua.y), bhi(ua.y) }; \
        float xv[4] = { blo(ux.x), bhi(ux.x), blo(ux.y), bhi(ux.y) }; \
        float* ar = acc[ni]; \
        _Pragma("unroll") \
        for (int j = 0; j < 4; ++j) { \
            ar[0] = fmaf(wlf[j].x, av[j], ar[0]); ar[1] = fmaf(wlf[j].y, av[j], ar[1]); \
            ar[2] = fmaf(wlf[j].z, av[j], ar[2]); ar[3] = fmaf(wlf[j].w, av[j], ar[3]); \
            ar[0] = fmaf(wrf[j].x, xv[j], ar[0]); ar[1] = fmaf(wrf[j].y, xv[j], ar[1]); \
            ar[2] = fmaf(wrf[j].z, xv[j], ar[2]); ar[3] = fmaf(wrf[j].w, xv[j], ar[3]); \
        } \
    } }

template<int CONV2>
__global__ __launch_bounds__(256) void k_gemm(
    const unsigned short* __restrict__ aggm,
    const unsigned short* __restrict__ selfb,   // conv1: xb, conv2: h1
    const unsigned short* __restrict__ wT,      // WlT | WrT bf16 [k][out]
    const float* __restrict__ bias1,            // conv1: b1l
    const float* __restrict__ biasA, const float* __restrict__ biasE,  // conv2
    const int* __restrict__ rowptr,
    unsigned short* __restrict__ h1, float* __restrict__ stats,
    const float* __restrict__ Wfc, const float* __restrict__ bfc,
    float* __restrict__ out)
{
    __shared__ __align__(16) char smem[33792];   // bf16 tiles 32KB; conv2 h3 [64][132] f32 aliases
    __shared__ int sRp[NT + 1];
    int t = threadIdx.x;
    int nb = blockIdx.x * NT;
    int ng = t >> 5, og = t & 31;
    int ng8 = ng * 8, og4 = og * 4;
    const unsigned short* WlT = wT;
    const unsigned short* WrT = wT + 16384;

    if (t < NT + 1) sRp[t] = rowptr[nb + t];
    {   // stage tiles: raw bf16 copies, coalesced uint4
        const uint4* srcA = (const uint4*)(aggm + (size_t)nb * F);
        const uint4* srcS = (const uint4*)(selfb + (size_t)nb * F);
        uint4* dA = (uint4*)smem;
        uint4* dS = (uint4*)(smem + 16384);
        #pragma unroll
        for (int i = 0; i < 4; ++i) {
            dA[t + i * 256] = srcA[t + i * 256];
            dS[t + i * 256] = srcS[t + i * 256];
        }
    }
    __syncthreads();

    float acc[8][4];
    #pragma unroll
    for (int i = 0; i < 8; ++i)
        #pragma unroll
        for (int j = 0; j < 4; ++j) acc[i][j] = 0.f;

    uint2 wlr[2][4], wrr[2][4];
    WLOAD(0, 0)
    for (int kk = 0; kk < F - 8; kk += 8) {
        WLOAD(1, kk + 4)
        KSTEP(0, kk)
        WLOAD(0, kk + 8)
        KSTEP(1, kk + 4)
    }
    WLOAD(1, F - 4)
    KSTEP(0, F - 8)
    KSTEP(1, F - 4)

    // ---- bias + row L2-norm (reduce over og lanes = 32-half of wave) ----
    float scl[8];
    {
        float4 ba, be;
        if constexpr (!CONV2) {
            ba = *(const float4*)&bias1[og4];
        } else {
            ba = *(const float4*)&biasA[og4];
            be = *(const float4*)&biasE[og4];
        }
        #pragma unroll
        for (int ni = 0; ni < 8; ++ni) {
            float* ar = acc[ni];
            if constexpr (!CONV2) {
                ar[0] += ba.x; ar[1] += ba.y; ar[2] += ba.z; ar[3] += ba.w;
            } else {
                float flg = (sRp[ng8 + ni + 1] > sRp[ng8 + ni]) ? 1.f : 0.f;
                ar[0] += ba.x + flg * be.x; ar[1] += ba.y + flg * be.y;
                ar[2] += ba.z + flg * be.z; ar[3] += ba.w + flg * be.w;
            }
            float s = ar[0]*ar[0] + ar[1]*ar[1] + ar[2]*ar[2] + ar[3]*ar[3];
            s += __shfl_xor(s, 1); s += __shfl_xor(s, 2); s += __shfl_xor(s, 4);
            s += __shfl_xor(s, 8); s += __shfl_xor(s, 16);
            scl[ni] = 1.f / fmaxf(sqrtf(s), 1e-12f);
        }
    }
    __syncthreads();   // all waves past k-loop LDS reads; smem reusable

    if constexpr (!CONV2) {
        // normalize + relu -> h1 (bf16); column partial stats via LDS
        float cs[4] = {0.f, 0.f, 0.f, 0.f}, cq[4] = {0.f, 0.f, 0.f, 0.f};
        #pragma unroll
        for (int ni = 0; ni < 8; ++ni) {
            float h0 = fmaxf(acc[ni][0] * scl[ni], 0.f);
            float h1v = fmaxf(acc[ni][1] * scl[ni], 0.f);
            float h2 = fmaxf(acc[ni][2] * scl[ni], 0.f);
            float h3 = fmaxf(acc[ni][3] * scl[ni], 0.f);
            cs[0] += h0; cs[1] += h1v; cs[2] += h2; cs[3] += h3;
            cq[0] = fmaf(h0, h0, cq[0]); cq[1] = fmaf(h1v, h1v, cq[1]);
            cq[2] = fmaf(h2, h2, cq[2]); cq[3] = fmaf(h3, h3, cq[3]);
            uint2 p; p.x = pk2(h0, h1v); p.y = pk2(h2, h3);
            *(uint2*)&h1[(size_t)(nb + ng8 + ni) * F + og4] = p;
        }
        float* sPS = (float*)smem;            // [8][128]
        float* sPQ = (float*)(smem + 4096);   // [8][128]
        #pragma unroll
        for (int o = 0; o < 4; ++o) {
            sPS[ng * 128 + og4 + o] = cs[o];
            sPQ[ng * 128 + og4 + o] = cq[o];
        }
        __syncthreads();
        if (t < F) {
            float s = 0.f, s2 = 0.f;
            #pragma unroll
            for (int g = 0; g < 8; ++g) {
                s += sPS[g * 128 + t];
                s2 += sPQ[g * 128 + t];
            }
            atomicAdd(&stats[t], s);
            atomicAdd(&stats[F + t], s2);
        }
    } else {
        // normalize -> h3 f32 in smem [64][132] -> fused fc
        float (*sC)[132] = (float(*)[132])smem;
        #pragma unroll
        for (int ni = 0; ni < 8; ++ni) {
            sC[ng8 + ni][og4]     = acc[ni][0] * scl[ni];
            sC[ng8 + ni][og4 + 1] = acc[ni][1] * scl[ni];
            sC[ng8 + ni][og4 + 2] = acc[ni][2] * scl[ni];
            sC[ng8 + ni][og4 + 3] = acc[ni][3] * scl[ni];
        }
        __syncthreads();
        #pragma unroll
        for (int pp = 0; pp < 4; ++pp) {
            int p = t + pp * 256;
            int n = p >> 4, c = p & 15;
            float s = bfc[c];
            for (int o = 0; o < F; o += 4) {
                float4 h4 = *(const float4*)&sC[n][o];
                float4 w4 = *(const float4*)&Wfc[c * F + o];
                s += h4.x * w4.x + h4.y * w4.y + h4.z * w4.z + h4.w * w4.w;
            }
            out[(size_t)(nb + n) * NC + c] = s;
        }
    }
}

extern "C" void kernel_launch(void* const* d_in, const int* in_sizes, int n_in,
                              void* d_out, int out_size, void* d_ws, size_t ws_size,
                              hipStream_t stream) {
    const float* x     = (const float*)d_in[0];
    const int*   ei    = (const int*)d_in[1];
    const float* W1l   = (const float*)d_in[2];
    const float* b1l   = (const float*)d_in[3];
    const float* W1r   = (const float*)d_in[4];
    const float* gamma = (const float*)d_in[5];
    const float* beta  = (const float*)d_in[6];
    const float* W2l   = (const float*)d_in[7];
    const float* b2l   = (const float*)d_in[8];
    const float* W2r   = (const float*)d_in[9];
    const float* Wfc   = (const float*)d_in[10];
    const float* bfc   = (const float*)d_in[11];

    char* ws = (char*)d_ws;
    int*            rowptr = (int*)(ws + OFF_ROWPTR);
    int*            fill   = (int*)(ws + OFF_FILL);
    int*            bsum   = (int*)(ws + OFF_BSUM);
    int*            sorted = (int*)(ws + OFF_SORTED);
    float*          stats  = (float*)(ws + OFF_STATS);
    unsigned short* w1T    = (unsigned short*)(ws + OFF_W1T);
    unsigned short* w2T    = (unsigned short*)(ws + OFF_W2T);
    unsigned short* xb     = (unsigned short*)(ws + OFF_XB);   // xb then h1 (same rows)
    unsigned short* aggm   = (unsigned short*)(ws + OFF_AGGM);
    float*          out    = (float*)d_out;

    hipMemsetAsync(fill, 0, NN * sizeof(int), stream);
    hipMemsetAsync(stats, 0, 256 * sizeof(float), stream);

    k_wprep1<<<128, 256, 0, stream>>>(W1l, W1r, w1T);
    k_x2b<<<NN * F / (256 * 8), 256, 0, stream>>>(x, xb);
    k_hist<<<(NE + 255) / 256, 256, 0, stream>>>(ei, fill);
    k_scan1<<<40, 1024, 0, stream>>>(fill, rowptr, bsum);
    k_scan2<<<1, 64, 0, stream>>>(bsum, rowptr);
    k_scan3<<<40, 1024, 0, stream>>>(rowptr, bsum, fill);
    k_scatter<<<(NE + 255) / 256, 256, 0, stream>>>(ei, fill, sorted);

    // conv1
    k_agg<<<NN / 4, 256, 0, stream>>>(xb, rowptr, sorted, aggm);
    k_gemm<0><<<NN / NT, 256, 0, stream>>>(aggm, xb, w1T, b1l, nullptr, nullptr,
                                           rowptr, xb, stats, nullptr, nullptr, nullptr);
    k_bnfinal<<<1, 128, 0, stream>>>(stats, gamma, beta);
    k_wprep2<<<1, 256, 0, stream>>>(W2l, W2r, b2l, stats, w2T);

    // conv2 (+ fused fc); h1 lives in xb buffer
    k_agg<<<NN / 4, 256, 0, stream>>>(xb, rowptr, sorted, aggm);
    k_gemm<1><<<NN / NT, 256, 0, stream>>>(aggm, xb, w2T, nullptr, stats, stats + 128,
                                           rowptr, nullptr, nullptr, Wfc, bfc, out);
}

// Round 11
// 276.985 us; speedup vs baseline: 3.7338x; 1.2189x over previous
//
#include <hip/hip_runtime.h>

#define NN 40000
#define NE 640000
#define F 128
#define NC 16
#define NT 32   // nodes per gemm block

typedef __attribute__((ext_vector_type(8))) short bf16x8;
typedef __attribute__((ext_vector_type(4))) float f32x4;

// ws layout (bytes); total 23501312 < proven 23632384
#define OFF_ROWPTR 0u          // (NN+1) ints
#define OFF_FILL   163968u     // NN ints
#define OFF_BSUM   327936u     // 64 ints
#define OFF_SORTED 328192u     // NE ints -> 2888192
#define OFF_STATS  2888192u    // 512 f32: [sum|bias2a][sumsq|biasExtra][bn_a][bn_b] (2048 B)
#define OFF_W1B    2890240u    // w1l | w1r bf16 [out][k] (64 KB contiguous)
#define OFF_W2B    2955776u    // w2l | w2r bf16 [out][k], BN-scaled (64 KB)
#define OFF_XB     3021312u    // NN*F bf16: xb, then h1 overwrites same rows (block-exclusive)
#define OFF_AGGM   13261312u   // NN*F bf16 -> 23501312

__device__ __forceinline__ unsigned short f2b(float f) {   // f32 -> bf16 RNE
    unsigned u = __builtin_bit_cast(unsigned, f);
    return (unsigned short)((u + 0x7fffu + ((u >> 16) & 1u)) >> 16);
}
__device__ __forceinline__ float b2f(unsigned short s) {
    return __builtin_bit_cast(float, (unsigned)s << 16);
}
__device__ __forceinline__ unsigned pk2(float lo, float hi) {
    return (unsigned)f2b(lo) | ((unsigned)f2b(hi) << 16);
}
__device__ __forceinline__ float blo(unsigned u) { return __builtin_bit_cast(float, u << 16); }
__device__ __forceinline__ float bhi(unsigned u) { return __builtin_bit_cast(float, u & 0xffff0000u); }

__global__ __launch_bounds__(256) void k_hist(const int* __restrict__ ei, int* __restrict__ cnt) {
    int e = blockIdx.x * 256 + threadIdx.x;
    if (e < NE) atomicAdd(&cnt[ei[NE + e]], 1);
}

__global__ __launch_bounds__(1024) void k_scan1(const int* __restrict__ cnt, int* __restrict__ rowptr,
                                                int* __restrict__ bsum) {
    __shared__ int wsum[16];
    int t = threadIdx.x, b = blockIdx.x;
    int idx = b * 1024 + t;
    int v = (idx < NN) ? cnt[idx] : 0;
    int lane = t & 63, w = t >> 6;
    int val = v;
    #pragma unroll
    for (int off = 1; off < 64; off <<= 1) { int u = __shfl_up(val, off); if (lane >= off) val += u; }
    if (lane == 63) wsum[w] = val;
    __syncthreads();
    if (w == 0) {
        int x = (lane < 16) ? wsum[lane] : 0;
        #pragma unroll
        for (int off = 1; off < 16; off <<= 1) { int u = __shfl_up(x, off); if (lane >= off) x += u; }
        if (lane < 16) wsum[lane] = x;
    }
    __syncthreads();
    int excl = val - v + (w > 0 ? wsum[w - 1] : 0);
    if (idx < NN) rowptr[idx] = excl;
    if (t == 1023) bsum[b] = wsum[15];
}

__global__ __launch_bounds__(64) void k_scan2(int* __restrict__ bsum, int* __restrict__ rowptr) {
    int lane = threadIdx.x;
    int v = (lane < 40) ? bsum[lane] : 0;
    int val = v;
    #pragma unroll
    for (int off = 1; off < 64; off <<= 1) { int u = __shfl_up(val, off); if (lane >= off) val += u; }
    if (lane < 40) bsum[lane] = val - v;
    if (lane == 0) rowptr[NN] = NE;
}

__global__ __launch_bounds__(1024) void k_scan3(int* __restrict__ rowptr, const int* __restrict__ bsum,
                                                int* __restrict__ fill) {
    int t = threadIdx.x, b = blockIdx.x;
    int idx = b * 1024 + t;
    if (idx < NN) {
        int r = rowptr[idx] + bsum[b];
        rowptr[idx] = r;
        fill[idx] = r;
    }
}

__global__ __launch_bounds__(256) void k_scatter(const int* __restrict__ ei, int* __restrict__ fill,
                                                 int* __restrict__ sorted) {
    int e = blockIdx.x * 256 + threadIdx.x;
    if (e < NE) {
        int src = ei[e], dst = ei[NE + e];
        int pos = atomicAdd(&fill[dst], 1);
        sorted[pos] = src;
    }
}

// W1l,W1r f32 -> bf16, natural [out][k] layout (r6-verified for MFMA B-frags)
__global__ __launch_bounds__(256) void k_wprep1(const float* __restrict__ W1l, const float* __restrict__ W1r,
                                                unsigned short* __restrict__ w1b) {
    int i = blockIdx.x * 256 + threadIdx.x;      // < 32768
    int m = i >> 14, rc = i & 16383;
    const float* src = (m == 0) ? W1l : W1r;
    w1b[i] = f2b(src[rc]);
}

// x (f32) -> xb (bf16), 8 elems/thread, coalesced
__global__ __launch_bounds__(256) void k_x2b(const float* __restrict__ x, unsigned short* __restrict__ xb) {
    int i = (blockIdx.x * 256 + threadIdx.x) * 8;
    float4 lo = *(const float4*)&x[i];
    float4 hi = *(const float4*)&x[i + 4];
    uint4 o;
    o.x = pk2(lo.x, lo.y); o.y = pk2(lo.z, lo.w);
    o.z = pk2(hi.x, hi.y); o.w = pk2(hi.z, hi.w);
    *(uint4*)&xb[i] = o;
}

__global__ __launch_bounds__(128) void k_bnfinal(float* __restrict__ stats, const float* __restrict__ gamma,
                                                 const float* __restrict__ beta) {
    int t = threadIdx.x;
    float mu  = stats[t] * (1.f / NN);
    float var = stats[F + t] * (1.f / NN) - mu * mu;
    float a = gamma[t] * rsqrtf(var + 1e-5f);
    stats[256 + t] = a;
    stats[384 + t] = beta[t] - mu * a;
}

// Fold BN into conv2 weights (bf16 [out][k], scaled) + bias vectors into stats[0..255]
// (sum/sumsq slots dead after bnfinal). stats[o]=bias2a, stats[128+o]=biasExtra.
__global__ __launch_bounds__(256) void k_wprep2(const float* __restrict__ W2l, const float* __restrict__ W2r,
                                                const float* __restrict__ b2l, float* __restrict__ stats,
                                                unsigned short* __restrict__ w2b) {
    int t = threadIdx.x;
    int o = t & 127;
    bool isL = t < 128;
    const float* W = isL ? W2l : W2r;
    unsigned short* dst = w2b + (isL ? 0 : 16384);
    float dot = 0.f;
    for (int k = 0; k < F; ++k) {
        float w = W[o * F + k];
        dst[o * F + k] = f2b(w * stats[256 + k]);
        dot = fmaf(stats[384 + k], w, dot);
    }
    if (isL) stats[128 + o] = dot;       // biasExtra (iff deg>0)
    else     stats[o] = b2l[o] + dot;    // bias2a (always)
}

// Gather (neighbor mean): one wave per node; quarter q, 4 rows in flight per lane.
__global__ __launch_bounds__(256) void k_agg(
    const unsigned short* __restrict__ featb,
    const int* __restrict__ rowptr, const int* __restrict__ sorted,
    unsigned short* __restrict__ aggm)
{
    int node = (blockIdx.x << 2) + (threadIdx.x >> 6);
    int lane = threadIdx.x & 63;
    int q = lane >> 4, li = lane & 15;
    int fo = li << 3;
    int e0 = rowptr[node], e1 = rowptr[node + 1];
    int deg = e1 - e0;
    float a0=0.f,a1=0.f,a2=0.f,a3=0.f,a4=0.f,a5=0.f,a6=0.f,a7=0.f;

#define ACC_EDGE(SRC) do { \
        uint4 u = *(const uint4*)&featb[(size_t)(SRC) * F + fo]; \
        a0 += blo(u.x); a1 += bhi(u.x); \
        a2 += blo(u.y); a3 += bhi(u.y); \
        a4 += blo(u.z); a5 += bhi(u.z); \
        a6 += blo(u.w); a7 += bhi(u.w); \
    } while (0)

    int e = e0;
    for (; e + 16 <= e1; e += 16) {
        int s0 = sorted[e + q];
        int s1 = sorted[e + 4 + q];
        int s2 = sorted[e + 8 + q];
        int s3 = sorted[e + 12 + q];
        ACC_EDGE(s0); ACC_EDGE(s1); ACC_EDGE(s2); ACC_EDGE(s3);
    }
    for (; e + 4 <= e1; e += 4) {
        int s0 = sorted[e + q];
        ACC_EDGE(s0);
    }
    if (e < e1 && q < (e1 - e)) {
        int s0 = sorted[e + q];
        ACC_EDGE(s0);
    }
#undef ACC_EDGE

    #pragma unroll
    for (int m = 16; m <= 32; m <<= 1) {
        a0 += __shfl_xor(a0, m); a1 += __shfl_xor(a1, m);
        a2 += __shfl_xor(a2, m); a3 += __shfl_xor(a3, m);
        a4 += __shfl_xor(a4, m); a5 += __shfl_xor(a5, m);
        a6 += __shfl_xor(a6, m); a7 += __shfl_xor(a7, m);
    }

    if (q == 0) {
        float inv = 1.f / (float)(deg > 1 ? deg : 1);
        uint4 o;
        o.x = pk2(a0 * inv, a1 * inv);
        o.y = pk2(a2 * inv, a3 * inv);
        o.z = pk2(a4 * inv, a5 * inv);
        o.w = pk2(a6 * inv, a7 * inv);
        *(uint4*)&aggm[(size_t)node * F + fo] = o;
    }
}

// MFMA dual GEMM: BOTH operands from LDS (r6 had A+B scattered-global, r7 A scattered,
// r8 B scattered — each ~100us latency-bound; this closes the 2x2).
// 32 nodes/block, 4 waves; LDS = weights 64KB + A-tiles 16KB = 80KB -> 2 blocks/CU.
// All staging coalesced uint4 + XOR swizzle (r8-verified); frag reads = ds_read_b128,
// swizzle xor constant per lane (rows congruent mod 8 across all frags).
// Wave w = col-pair cp: cols [cp*32, cp*32+32), all 32 rows; 32 ds_reads + 32 MFMAs.
template<int CONV2>
__global__ __launch_bounds__(256) void k_gemm(
    const unsigned short* __restrict__ aggm,
    const unsigned short* __restrict__ selfb,   // conv1: xb, conv2: h1
    const unsigned short* __restrict__ wb,      // wl | wr bf16 [out][k], 64KB
    const float* __restrict__ bias1,            // conv1: b1l
    const float* __restrict__ biasA, const float* __restrict__ biasE,  // conv2
    const int* __restrict__ rowptr,
    unsigned short* __restrict__ h1, float* __restrict__ stats,
    const float* __restrict__ Wfc, const float* __restrict__ bfc,
    float* __restrict__ out)
{
    __shared__ __align__(16) char smem[81920];  // [0,64K) weights wl|wr; [64K,80K) A agg|self
    int t = threadIdx.x;
    int nb = blockIdx.x * NT;
    int cp = t >> 6, lane = t & 63;
    int li = lane & 15, kg = lane >> 4;

    // ---- stage: all coalesced, swizzled LDS writes ----
    {
        const uint4* srcW = (const uint4*)wb;
        #pragma unroll
        for (int i = 0; i < 16; ++i) {
            unsigned d = (unsigned)(i * 256 + t) * 16u;
            uint4 v = srcW[i * 256 + t];
            *(uint4*)(smem + (d ^ (((d >> 8) & 7u) << 4))) = v;
        }
        const uint4* srcA = (const uint4*)(aggm + (size_t)nb * F);
        const uint4* srcS = (const uint4*)(selfb + (size_t)nb * F);
        #pragma unroll
        for (int i = 0; i < 2; ++i) {
            unsigned d = (unsigned)(i * 256 + t) * 16u;
            uint4 va = srcA[i * 256 + t];
            uint4 vs = srcS[i * 256 + t];
            unsigned sw = d ^ (((d >> 8) & 7u) << 4);
            *(uint4*)(smem + 65536u + sw) = va;
            *(uint4*)(smem + 73728u + sw) = vs;
        }
    }
    __syncthreads();

    // ---- MFMA: K=128 x 2 paths, everything ds_read_b128 ----
    f32x4 acc00 = {0.f,0.f,0.f,0.f}, acc01 = {0.f,0.f,0.f,0.f};
    f32x4 acc10 = {0.f,0.f,0.f,0.f}, acc11 = {0.f,0.f,0.f,0.f};
    unsigned swz = ((unsigned)(li & 7) << 4);
    #pragma unroll
    for (int path = 0; path < 2; ++path) {
        unsigned aBase = 65536u + (path ? 8192u : 0u);
        unsigned bBase = path ? 32768u : 0u;
        #pragma unroll
        for (int kc = 0; kc < 4; ++kc) {
            unsigned koff = (unsigned)(kg * 16 + kc * 64);
            bf16x8 a0 = *(const bf16x8*)(smem + aBase + (((unsigned)li * 256u + koff) ^ swz));
            bf16x8 a1 = *(const bf16x8*)(smem + aBase + (((unsigned)(16 + li) * 256u + koff) ^ swz));
            bf16x8 b0 = *(const bf16x8*)(smem + bBase + (((unsigned)(cp * 32 + li) * 256u + koff) ^ swz));
            bf16x8 b1 = *(const bf16x8*)(smem + bBase + (((unsigned)(cp * 32 + 16 + li) * 256u + koff) ^ swz));
            acc00 = __builtin_amdgcn_mfma_f32_16x16x32_bf16(a0, b0, acc00, 0, 0, 0);
            acc01 = __builtin_amdgcn_mfma_f32_16x16x32_bf16(a0, b1, acc01, 0, 0, 0);
            acc10 = __builtin_amdgcn_mfma_f32_16x16x32_bf16(a1, b0, acc10, 0, 0, 0);
            acc11 = __builtin_amdgcn_mfma_f32_16x16x32_bf16(a1, b1, acc11, 0, 0, 0);
        }
    }
    __syncthreads();   // all LDS frag reads done -> smem reusable

    // ---- C -> sC (aliases weight region). Layout (r6-verified): reg r -> row kg*4+r, col li ----
    float (*sC)[132] = (float(*)[132])smem;
    #pragma unroll
    for (int r = 0; r < 4; ++r) {
        sC[kg * 4 + r][cp * 32 + li]           = acc00[r];
        sC[kg * 4 + r][cp * 32 + 16 + li]      = acc01[r];
        sC[16 + kg * 4 + r][cp * 32 + li]      = acc10[r];
        sC[16 + kg * 4 + r][cp * 32 + 16 + li] = acc11[r];
    }
    __syncthreads();

    // ---- bias + row L2 norm: thread t -> row t>>3, cols (t&7)*16..+16 (r6-proven) ----
    int row = t >> 3, cb = (t & 7) * 16;
    int node = nb + row;
    float v[16];
    float ss = 0.f;
    if constexpr (!CONV2) {
        #pragma unroll
        for (int j = 0; j < 16; ++j) {
            v[j] = sC[row][cb + j] + bias1[cb + j];
            ss = fmaf(v[j], v[j], ss);
        }
    } else {
        float flag = (rowptr[node + 1] > rowptr[node]) ? 1.f : 0.f;
        #pragma unroll
        for (int j = 0; j < 16; ++j) {
            v[j] = sC[row][cb + j] + biasA[cb + j] + flag * biasE[cb + j];
            ss = fmaf(v[j], v[j], ss);
        }
    }
    ss += __shfl_xor(ss, 1); ss += __shfl_xor(ss, 2); ss += __shfl_xor(ss, 4);
    float sc = 1.f / fmaxf(sqrtf(ss), 1e-12f);

    if constexpr (!CONV2) {
        #pragma unroll
        for (int j = 0; j < 16; ++j) {
            v[j] = fmaxf(v[j] * sc, 0.f);       // normalize then relu
            sC[row][cb + j] = v[j];             // f32 for BN stats
        }
        uint4 p0, p1;
        p0.x = pk2(v[0], v[1]);   p0.y = pk2(v[2], v[3]);
        p0.z = pk2(v[4], v[5]);   p0.w = pk2(v[6], v[7]);
        p1.x = pk2(v[8], v[9]);   p1.y = pk2(v[10], v[11]);
        p1.z = pk2(v[12], v[13]); p1.w = pk2(v[14], v[15]);
        *(uint4*)&h1[(size_t)node * F + cb]     = p0;
        *(uint4*)&h1[(size_t)node * F + cb + 8] = p1;
        __syncthreads();
        if (t < F) {
            float s = 0.f, s2 = 0.f;
            #pragma unroll
            for (int r = 0; r < NT; ++r) {
                float h = sC[r][t];
                s += h; s2 = fmaf(h, h, s2);
            }
            atomicAdd(&stats[t], s);
            atomicAdd(&stats[F + t], s2);
        }
    } else {
        #pragma unroll
        for (int j = 0; j < 16; ++j) sC[row][cb + j] = v[j] * sc;
        __syncthreads();
        #pragma unroll
        for (int pp = 0; pp < 2; ++pp) {
            int p = t + pp * 256;
            int n = p >> 4, c = p & 15;
            float s = bfc[c];
            for (int o = 0; o < F; o += 4) {
                float4 h4 = *(const float4*)&sC[n][o];
                float4 w4 = *(const float4*)&Wfc[c * F + o];
                s += h4.x * w4.x + h4.y * w4.y + h4.z * w4.z + h4.w * w4.w;
            }
            out[(size_t)(nb + n) * NC + c] = s;
        }
    }
}

extern "C" void kernel_launch(void* const* d_in, const int* in_sizes, int n_in,
                              void* d_out, int out_size, void* d_ws, size_t ws_size,
                              hipStream_t stream) {
    const float* x     = (const float*)d_in[0];
    const int*   ei    = (const int*)d_in[1];
    const float* W1l   = (const float*)d_in[2];
    const float* b1l   = (const float*)d_in[3];
    const float* W1r   = (const float*)d_in[4];
    const float* gamma = (const float*)d_in[5];
    const float* beta  = (const float*)d_in[6];
    const float* W2l   = (const float*)d_in[7];
    const float* b2l   = (const float*)d_in[8];
    const float* W2r   = (const float*)d_in[9];
    const float* Wfc   = (const float*)d_in[10];
    const float* bfc   = (const float*)d_in[11];

    char* ws = (char*)d_ws;
    int*            rowptr = (int*)(ws + OFF_ROWPTR);
    int*            fill   = (int*)(ws + OFF_FILL);
    int*            bsum   = (int*)(ws + OFF_BSUM);
    int*            sorted = (int*)(ws + OFF_SORTED);
    float*          stats  = (float*)(ws + OFF_STATS);
    unsigned short* w1b    = (unsigned short*)(ws + OFF_W1B);
    unsigned short* w2b    = (unsigned short*)(ws + OFF_W2B);
    unsigned short* xb     = (unsigned short*)(ws + OFF_XB);   // xb then h1 (same rows)
    unsigned short* aggm   = (unsigned short*)(ws + OFF_AGGM);
    float*          out    = (float*)d_out;

    hipMemsetAsync(fill, 0, NN * sizeof(int), stream);
    hipMemsetAsync(stats, 0, 256 * sizeof(float), stream);

    k_wprep1<<<128, 256, 0, stream>>>(W1l, W1r, w1b);
    k_x2b<<<NN * F / (256 * 8), 256, 0, stream>>>(x, xb);
    k_hist<<<(NE + 255) / 256, 256, 0, stream>>>(ei, fill);
    k_scan1<<<40, 1024, 0, stream>>>(fill, rowptr, bsum);
    k_scan2<<<1, 64, 0, stream>>>(bsum, rowptr);
    k_scan3<<<40, 1024, 0, stream>>>(rowptr, bsum, fill);
    k_scatter<<<(NE + 255) / 256, 256, 0, stream>>>(ei, fill, sorted);

    // conv1
    k_agg<<<NN / 4, 256, 0, stream>>>(xb, rowptr, sorted, aggm);
    k_gemm<0><<<NN / NT, 256, 0, stream>>>(aggm, xb, w1b, b1l, nullptr, nullptr,
                                           rowptr, xb, stats, nullptr, nullptr, nullptr);
    k_bnfinal<<<1, 128, 0, stream>>>(stats, gamma, beta);
    k_wprep2<<<1, 256, 0, stream>>>(W2l, W2r, b2l, stats, w2b);

    // conv2 (+ fused fc); h1 lives in xb buffer
    k_agg<<<NN / 4, 256, 0, stream>>>(xb, rowptr, sorted, aggm);
    k_gemm<1><<<NN / NT, 256, 0, stream>>>(aggm, xb, w2b, nullptr, stats, stats + 128,
                                           rowptr, nullptr, nullptr, Wfc, bfc, out);
}

// Round 12
// 189.620 us; speedup vs baseline: 5.4541x; 1.4607x over previous
//
#include <hip/hip_runtime.h>

#define NN 40000
#define NE 640000
#define F 128
#define NC 16
#define NT 32    // nodes per tile
#define TPB 5    // tiles per persistent block (250 blocks x 5 x 32 = 40000)

typedef __attribute__((ext_vector_type(8))) short bf16x8;
typedef __attribute__((ext_vector_type(4))) float f32x4;

// ws layout (bytes); total 23501312 < proven 23632384
#define OFF_ROWPTR 0u
#define OFF_FILL   163968u
#define OFF_BSUM   327936u
#define OFF_SORTED 328192u
#define OFF_STATS  2888192u    // 512 f32: [sum|bias2a][sumsq|biasExtra][bn_a][bn_b]
#define OFF_W1B    2890240u    // w1l | w1r bf16 [out][k] (64 KB)
#define OFF_W2B    2955776u    // w2l | w2r bf16 [out][k], BN-scaled (64 KB)
#define OFF_XB     3021312u    // NN*F bf16: xb, then h1 overwrites same rows
#define OFF_AGGM   13261312u   // NN*F bf16

// LDS regions (k_gemm)
#define SM_W   0u        // weights 64 KB (swizzled image)
#define SM_A0  65536u    // A dbuf 0: agg 8K | self 8K
#define SM_A1  81920u    // A dbuf 1
#define SM_C   98304u    // sC [32][132] f32 = 16896 B
#define SM_TOT 115200u

#define GLL(gsrc, ldst) \
    __builtin_amdgcn_global_load_lds((const __attribute__((address_space(1))) void*)(gsrc), \
        (__attribute__((address_space(3))) void*)(ldst), 16, 0, 0)

__device__ __forceinline__ unsigned short f2b(float f) {   // f32 -> bf16 RNE
    unsigned u = __builtin_bit_cast(unsigned, f);
    return (unsigned short)((u + 0x7fffu + ((u >> 16) & 1u)) >> 16);
}
__device__ __forceinline__ float b2f(unsigned short s) {
    return __builtin_bit_cast(float, (unsigned)s << 16);
}
__device__ __forceinline__ unsigned pk2(float lo, float hi) {
    return (unsigned)f2b(lo) | ((unsigned)f2b(hi) << 16);
}
__device__ __forceinline__ float blo(unsigned u) { return __builtin_bit_cast(float, u << 16); }
__device__ __forceinline__ float bhi(unsigned u) { return __builtin_bit_cast(float, u & 0xffff0000u); }

__global__ __launch_bounds__(256) void k_hist(const int* __restrict__ ei, int* __restrict__ cnt) {
    int e = blockIdx.x * 256 + threadIdx.x;
    if (e < NE) atomicAdd(&cnt[ei[NE + e]], 1);
}

__global__ __launch_bounds__(1024) void k_scan1(const int* __restrict__ cnt, int* __restrict__ rowptr,
                                                int* __restrict__ bsum) {
    __shared__ int wsum[16];
    int t = threadIdx.x, b = blockIdx.x;
    int idx = b * 1024 + t;
    int v = (idx < NN) ? cnt[idx] : 0;
    int lane = t & 63, w = t >> 6;
    int val = v;
    #pragma unroll
    for (int off = 1; off < 64; off <<= 1) { int u = __shfl_up(val, off); if (lane >= off) val += u; }
    if (lane == 63) wsum[w] = val;
    __syncthreads();
    if (w == 0) {
        int x = (lane < 16) ? wsum[lane] : 0;
        #pragma unroll
        for (int off = 1; off < 16; off <<= 1) { int u = __shfl_up(x, off); if (lane >= off) x += u; }
        if (lane < 16) wsum[lane] = x;
    }
    __syncthreads();
    int excl = val - v + (w > 0 ? wsum[w - 1] : 0);
    if (idx < NN) rowptr[idx] = excl;
    if (t == 1023) bsum[b] = wsum[15];
}

__global__ __launch_bounds__(64) void k_scan2(int* __restrict__ bsum, int* __restrict__ rowptr) {
    int lane = threadIdx.x;
    int v = (lane < 40) ? bsum[lane] : 0;
    int val = v;
    #pragma unroll
    for (int off = 1; off < 64; off <<= 1) { int u = __shfl_up(val, off); if (lane >= off) val += u; }
    if (lane < 40) bsum[lane] = val - v;
    if (lane == 0) rowptr[NN] = NE;
}

__global__ __launch_bounds__(1024) void k_scan3(int* __restrict__ rowptr, const int* __restrict__ bsum,
                                                int* __restrict__ fill) {
    int t = threadIdx.x, b = blockIdx.x;
    int idx = b * 1024 + t;
    if (idx < NN) {
        int r = rowptr[idx] + bsum[b];
        rowptr[idx] = r;
        fill[idx] = r;
    }
}

__global__ __launch_bounds__(256) void k_scatter(const int* __restrict__ ei, int* __restrict__ fill,
                                                 int* __restrict__ sorted) {
    int e = blockIdx.x * 256 + threadIdx.x;
    if (e < NE) {
        int src = ei[e], dst = ei[NE + e];
        int pos = atomicAdd(&fill[dst], 1);
        sorted[pos] = src;
    }
}

__global__ __launch_bounds__(256) void k_wprep1(const float* __restrict__ W1l, const float* __restrict__ W1r,
                                                unsigned short* __restrict__ w1b) {
    int i = blockIdx.x * 256 + threadIdx.x;      // < 32768
    int m = i >> 14, rc = i & 16383;
    const float* src = (m == 0) ? W1l : W1r;
    w1b[i] = f2b(src[rc]);
}

__global__ __launch_bounds__(256) void k_x2b(const float* __restrict__ x, unsigned short* __restrict__ xb) {
    int i = (blockIdx.x * 256 + threadIdx.x) * 8;
    float4 lo = *(const float4*)&x[i];
    float4 hi = *(const float4*)&x[i + 4];
    uint4 o;
    o.x = pk2(lo.x, lo.y); o.y = pk2(lo.z, lo.w);
    o.z = pk2(hi.x, hi.y); o.w = pk2(hi.z, hi.w);
    *(uint4*)&xb[i] = o;
}

__global__ __launch_bounds__(128) void k_bnfinal(float* __restrict__ stats, const float* __restrict__ gamma,
                                                 const float* __restrict__ beta) {
    int t = threadIdx.x;
    float mu  = stats[t] * (1.f / NN);
    float var = stats[F + t] * (1.f / NN) - mu * mu;
    float a = gamma[t] * rsqrtf(var + 1e-5f);
    stats[256 + t] = a;
    stats[384 + t] = beta[t] - mu * a;
}

__global__ __launch_bounds__(256) void k_wprep2(const float* __restrict__ W2l, const float* __restrict__ W2r,
                                                const float* __restrict__ b2l, float* __restrict__ stats,
                                                unsigned short* __restrict__ w2b) {
    int t = threadIdx.x;
    int o = t & 127;
    bool isL = t < 128;
    const float* W = isL ? W2l : W2r;
    unsigned short* dst = w2b + (isL ? 0 : 16384);
    float dot = 0.f;
    for (int k = 0; k < F; ++k) {
        float w = W[o * F + k];
        dst[o * F + k] = f2b(w * stats[256 + k]);
        dot = fmaf(stats[384 + k], w, dot);
    }
    if (isL) stats[128 + o] = dot;       // biasExtra (iff deg>0)
    else     stats[o] = b2l[o] + dot;    // bias2a (always)
}

// Gather (neighbor mean): one wave per node; quarter q, 4 rows in flight per lane.
__global__ __launch_bounds__(256) void k_agg(
    const unsigned short* __restrict__ featb,
    const int* __restrict__ rowptr, const int* __restrict__ sorted,
    unsigned short* __restrict__ aggm)
{
    int node = (blockIdx.x << 2) + (threadIdx.x >> 6);
    int lane = threadIdx.x & 63;
    int q = lane >> 4, li = lane & 15;
    int fo = li << 3;
    int e0 = rowptr[node], e1 = rowptr[node + 1];
    int deg = e1 - e0;
    float a0=0.f,a1=0.f,a2=0.f,a3=0.f,a4=0.f,a5=0.f,a6=0.f,a7=0.f;

#define ACC_EDGE(SRC) do { \
        uint4 u = *(const uint4*)&featb[(size_t)(SRC) * F + fo]; \
        a0 += blo(u.x); a1 += bhi(u.x); \
        a2 += blo(u.y); a3 += bhi(u.y); \
        a4 += blo(u.z); a5 += bhi(u.z); \
        a6 += blo(u.w); a7 += bhi(u.w); \
    } while (0)

    int e = e0;
    for (; e + 16 <= e1; e += 16) {
        int s0 = sorted[e + q];
        int s1 = sorted[e + 4 + q];
        int s2 = sorted[e + 8 + q];
        int s3 = sorted[e + 12 + q];
        ACC_EDGE(s0); ACC_EDGE(s1); ACC_EDGE(s2); ACC_EDGE(s3);
    }
    for (; e + 4 <= e1; e += 4) {
        int s0 = sorted[e + q];
        ACC_EDGE(s0);
    }
    if (e < e1 && q < (e1 - e)) {
        int s0 = sorted[e + q];
        ACC_EDGE(s0);
    }
#undef ACC_EDGE

    #pragma unroll
    for (int m = 16; m <= 32; m <<= 1) {
        a0 += __shfl_xor(a0, m); a1 += __shfl_xor(a1, m);
        a2 += __shfl_xor(a2, m); a3 += __shfl_xor(a3, m);
        a4 += __shfl_xor(a4, m); a5 += __shfl_xor(a5, m);
        a6 += __shfl_xor(a6, m); a7 += __shfl_xor(a7, m);
    }

    if (q == 0) {
        float inv = 1.f / (float)(deg > 1 ? deg : 1);
        uint4 o;
        o.x = pk2(a0 * inv, a1 * inv);
        o.y = pk2(a2 * inv, a3 * inv);
        o.z = pk2(a4 * inv, a5 * inv);
        o.w = pk2(a6 * inv, a7 * inv);
        *(uint4*)&aggm[(size_t)node * F + fo] = o;
    }
}

// Persistent MFMA dual GEMM. 250 blocks; each stages 64KB weights ONCE (async
// global_load_lds, linear LDS dest + pre-swizzled per-lane source = same LDS image as
// r11's verified swizzle), then loops 5 tiles of 32 nodes with double-buffered A
// (2-phase template: STAGE next -> COMPUTE cur -> barrier; stage latency hides under MFMA).
template<int CONV2>
__global__ __launch_bounds__(256) void k_gemm(
    const unsigned short* __restrict__ aggm,
    const unsigned short* __restrict__ selfb,   // conv1: xb, conv2: h1
    const unsigned short* __restrict__ wb,      // wl | wr bf16 [out][k], 64KB
    const float* __restrict__ bias1,
    const float* __restrict__ biasA, const float* __restrict__ biasE,
    const int* __restrict__ rowptr,
    unsigned short* __restrict__ h1, float* __restrict__ stats,
    const float* __restrict__ Wfc, const float* __restrict__ bfc,
    float* __restrict__ out)
{
    __shared__ __align__(16) char smem[SM_TOT];
    int t = threadIdx.x;
    int nb0 = blockIdx.x * (NT * TPB);
    int w = t >> 6, lane = t & 63;
    int li = lane & 15, kg = lane >> 4;
    float (*sC)[132] = (float(*)[132])(smem + SM_C);

    // ---- weight stage (once): 16 async 1KB calls per wave ----
    {
        const char* wsrc = (const char*)wb;
        #pragma unroll
        for (int i = 0; i < 16; ++i) {
            unsigned Lb = (unsigned)(w * 16384 + i * 1024);
            unsigned s = Lb + (unsigned)lane * 16u;
            unsigned g = s ^ (((s >> 8) & 7u) << 4);
            GLL(wsrc + g, smem + Lb);
        }
    }

#define STAGE_A(TI, BUF) { \
        size_t rowb = (size_t)(nb0 + (TI) * NT) * 256u; \
        const char* asrc_ = (const char*)aggm + rowb; \
        const char* ssrc_ = (const char*)selfb + rowb; \
        _Pragma("unroll") \
        for (int i_ = 0; i_ < 2; ++i_) { \
            unsigned q_ = (unsigned)(w * 2048 + i_ * 1024); \
            unsigned s_ = q_ + (unsigned)lane * 16u; \
            unsigned g_ = s_ ^ (((s_ >> 8) & 7u) << 4); \
            GLL(asrc_ + g_, smem + (BUF) + q_); \
            GLL(ssrc_ + g_, smem + (BUF) + 8192u + q_); \
        } }

    STAGE_A(0, SM_A0)
    __syncthreads();   // compiler drains vmcnt before barrier: weights + tile0 in LDS

    float sAcc = 0.f, s2Acc = 0.f;   // conv1 BN stats, accumulated across tiles
    int cp = w;
    unsigned swz = ((unsigned)(li & 7) << 4);

    for (int tt = 0; tt < TPB; ++tt) {
        unsigned bufC = (tt & 1) ? SM_A1 : SM_A0;
        unsigned bufN = (tt & 1) ? SM_A0 : SM_A1;
        if (tt + 1 < TPB) STAGE_A(tt + 1, bufN)   // async, lands by next barrier

        int nb = nb0 + tt * NT;

        // ---- MFMA: wave cp -> cols [cp*32, cp*32+32), rows 0..31 ----
        f32x4 acc00 = {0.f,0.f,0.f,0.f}, acc01 = {0.f,0.f,0.f,0.f};
        f32x4 acc10 = {0.f,0.f,0.f,0.f}, acc11 = {0.f,0.f,0.f,0.f};
        #pragma unroll
        for (int path = 0; path < 2; ++path) {
            unsigned aBase = bufC + (path ? 8192u : 0u);
            unsigned bBase = path ? 32768u : 0u;
            #pragma unroll
            for (int kc = 0; kc < 4; ++kc) {
                unsigned koff = (unsigned)(kg * 16 + kc * 64);
                bf16x8 a0 = *(const bf16x8*)(smem + aBase + (((unsigned)li * 256u + koff) ^ swz));
                bf16x8 a1 = *(const bf16x8*)(smem + aBase + (((unsigned)(16 + li) * 256u + koff) ^ swz));
                bf16x8 b0 = *(const bf16x8*)(smem + bBase + (((unsigned)(cp * 32 + li) * 256u + koff) ^ swz));
                bf16x8 b1 = *(const bf16x8*)(smem + bBase + (((unsigned)(cp * 32 + 16 + li) * 256u + koff) ^ swz));
                acc00 = __builtin_amdgcn_mfma_f32_16x16x32_bf16(a0, b0, acc00, 0, 0, 0);
                acc01 = __builtin_amdgcn_mfma_f32_16x16x32_bf16(a0, b1, acc01, 0, 0, 0);
                acc10 = __builtin_amdgcn_mfma_f32_16x16x32_bf16(a1, b0, acc10, 0, 0, 0);
                acc11 = __builtin_amdgcn_mfma_f32_16x16x32_bf16(a1, b1, acc11, 0, 0, 0);
            }
        }
        __syncthreads();   // B1: all compute-cur done; next-tile async loads drained

        // ---- C -> sC (layout r6/r11-verified: reg r -> row kg*4+r, col li) ----
        #pragma unroll
        for (int r = 0; r < 4; ++r) {
            sC[kg * 4 + r][cp * 32 + li]           = acc00[r];
            sC[kg * 4 + r][cp * 32 + 16 + li]      = acc01[r];
            sC[16 + kg * 4 + r][cp * 32 + li]      = acc10[r];
            sC[16 + kg * 4 + r][cp * 32 + 16 + li] = acc11[r];
        }
        __syncthreads();   // B2

        // ---- bias + row L2 norm: thread -> row t>>3, cols (t&7)*16..+16 ----
        int row = t >> 3, cb = (t & 7) * 16;
        int node = nb + row;
        float v[16];
        float ss = 0.f;
        if constexpr (!CONV2) {
            #pragma unroll
            for (int j = 0; j < 16; ++j) {
                v[j] = sC[row][cb + j] + bias1[cb + j];
                ss = fmaf(v[j], v[j], ss);
            }
        } else {
            float flag = (rowptr[node + 1] > rowptr[node]) ? 1.f : 0.f;
            #pragma unroll
            for (int j = 0; j < 16; ++j) {
                v[j] = sC[row][cb + j] + biasA[cb + j] + flag * biasE[cb + j];
                ss = fmaf(v[j], v[j], ss);
            }
        }
        ss += __shfl_xor(ss, 1); ss += __shfl_xor(ss, 2); ss += __shfl_xor(ss, 4);
        float sc = 1.f / fmaxf(sqrtf(ss), 1e-12f);

        if constexpr (!CONV2) {
            #pragma unroll
            for (int j = 0; j < 16; ++j) {
                v[j] = fmaxf(v[j] * sc, 0.f);       // normalize then relu
                sC[row][cb + j] = v[j];             // f32 for BN stats
            }
            uint4 p0, p1;
            p0.x = pk2(v[0], v[1]);   p0.y = pk2(v[2], v[3]);
            p0.z = pk2(v[4], v[5]);   p0.w = pk2(v[6], v[7]);
            p1.x = pk2(v[8], v[9]);   p1.y = pk2(v[10], v[11]);
            p1.z = pk2(v[12], v[13]); p1.w = pk2(v[14], v[15]);
            *(uint4*)&h1[(size_t)node * F + cb]     = p0;
            *(uint4*)&h1[(size_t)node * F + cb + 8] = p1;
            __syncthreads();   // B3: normalized sC visible for stats
            if (t < F) {
                #pragma unroll
                for (int r = 0; r < NT; ++r) {
                    float h = sC[r][t];
                    sAcc += h; s2Acc = fmaf(h, h, s2Acc);
                }
            }
        } else {
            #pragma unroll
            for (int j = 0; j < 16; ++j) sC[row][cb + j] = v[j] * sc;
            __syncthreads();   // B3: normalized sC visible for fc
            #pragma unroll
            for (int pp = 0; pp < 2; ++pp) {
                int p = t + pp * 256;
                int n = p >> 4, c = p & 15;
                float s = bfc[c];
                for (int o = 0; o < F; o += 4) {
                    float4 h4 = *(const float4*)&sC[n][o];
                    float4 w4 = *(const float4*)&Wfc[c * F + o];
                    s += h4.x * w4.x + h4.y * w4.y + h4.z * w4.z + h4.w * w4.w;
                }
                out[(size_t)(nb + n) * NC + c] = s;
            }
        }
        // next iteration's B1 protects sC reuse and buffer swap
    }

    if constexpr (!CONV2) {
        if (t < F) {
            atomicAdd(&stats[t], sAcc);
            atomicAdd(&stats[F + t], s2Acc);
        }
    }
#undef STAGE_A
}

extern "C" void kernel_launch(void* const* d_in, const int* in_sizes, int n_in,
                              void* d_out, int out_size, void* d_ws, size_t ws_size,
                              hipStream_t stream) {
    const float* x     = (const float*)d_in[0];
    const int*   ei    = (const int*)d_in[1];
    const float* W1l   = (const float*)d_in[2];
    const float* b1l   = (const float*)d_in[3];
    const float* W1r   = (const float*)d_in[4];
    const float* gamma = (const float*)d_in[5];
    const float* beta  = (const float*)d_in[6];
    const float* W2l   = (const float*)d_in[7];
    const float* b2l   = (const float*)d_in[8];
    const float* W2r   = (const float*)d_in[9];
    const float* Wfc   = (const float*)d_in[10];
    const float* bfc   = (const float*)d_in[11];

    char* ws = (char*)d_ws;
    int*            rowptr = (int*)(ws + OFF_ROWPTR);
    int*            fill   = (int*)(ws + OFF_FILL);
    int*            bsum   = (int*)(ws + OFF_BSUM);
    int*            sorted = (int*)(ws + OFF_SORTED);
    float*          stats  = (float*)(ws + OFF_STATS);
    unsigned short* w1b    = (unsigned short*)(ws + OFF_W1B);
    unsigned short* w2b    = (unsigned short*)(ws + OFF_W2B);
    unsigned short* xb     = (unsigned short*)(ws + OFF_XB);   // xb then h1 (same rows)
    unsigned short* aggm   = (unsigned short*)(ws + OFF_AGGM);
    float*          out    = (float*)d_out;

    hipMemsetAsync(fill, 0, NN * sizeof(int), stream);
    hipMemsetAsync(stats, 0, 256 * sizeof(float), stream);

    k_wprep1<<<128, 256, 0, stream>>>(W1l, W1r, w1b);
    k_x2b<<<NN * F / (256 * 8), 256, 0, stream>>>(x, xb);
    k_hist<<<(NE + 255) / 256, 256, 0, stream>>>(ei, fill);
    k_scan1<<<40, 1024, 0, stream>>>(fill, rowptr, bsum);
    k_scan2<<<1, 64, 0, stream>>>(bsum, rowptr);
    k_scan3<<<40, 1024, 0, stream>>>(rowptr, bsum, fill);
    k_scatter<<<(NE + 255) / 256, 256, 0, stream>>>(ei, fill, sorted);

    // conv1
    k_agg<<<NN / 4, 256, 0, stream>>>(xb, rowptr, sorted, aggm);
    k_gemm<0><<<NN / (NT * TPB), 256, 0, stream>>>(aggm, xb, w1b, b1l, nullptr, nullptr,
                                                   rowptr, xb, stats, nullptr, nullptr, nullptr);
    k_bnfinal<<<1, 128, 0, stream>>>(stats, gamma, beta);
    k_wprep2<<<1, 256, 0, stream>>>(W2l, W2r, b2l, stats, w2b);

    // conv2 (+ fused fc); h1 lives in xb buffer
    k_agg<<<NN / 4, 256, 0, stream>>>(xb, rowptr, sorted, aggm);
    k_gemm<1><<<NN / (NT * TPB), 256, 0, stream>>>(aggm, xb, w2b, nullptr, stats, stats + 128,
                                                   rowptr, nullptr, nullptr, Wfc, bfc, out);
}

// Round 13
// 185.545 us; speedup vs baseline: 5.5739x; 1.0220x over previous
//
#include <hip/hip_runtime.h>

#define NN 40000
#define NE 640000
#define F 128
#define NC 16
#define NT 32    // nodes per tile
#define TPB 5    // tiles per persistent block (250 blocks x 5 x 32 = 40000)

typedef __attribute__((ext_vector_type(8))) short bf16x8;
typedef __attribute__((ext_vector_type(4))) float f32x4;

// ws layout (bytes); total 23501312 < proven 23632384
#define OFF_ROWPTR 0u
#define OFF_FILL   163968u
#define OFF_BSUM   327936u
#define OFF_SORTED 328192u
#define OFF_STATS  2888192u    // 512 f32: [sum|bias2a][sumsq|biasExtra][bn_a][bn_b]
#define OFF_W1B    2890240u    // w1l | w1r bf16 [out][k] (64 KB)
#define OFF_W2B    2955776u    // w2l | w2r bf16 [out][k], BN-scaled (64 KB)
#define OFF_XB     3021312u    // NN*F bf16: xb, then h1 overwrites same rows
#define OFF_AGGM   13261312u   // NN*F bf16

// LDS regions (k_gemm)
#define SM_W   0u        // weights 64 KB (swizzled image)
#define SM_A0  65536u    // A dbuf 0: agg 8K | self 8K
#define SM_A1  81920u    // A dbuf 1
#define SM_C   98304u    // sC [32][132] f32 = 16896 B
#define SM_TOT 115200u

#define GLL(gsrc, ldst) \
    __builtin_amdgcn_global_load_lds((const __attribute__((address_space(1))) void*)(gsrc), \
        (__attribute__((address_space(3))) void*)(ldst), 16, 0, 0)

__device__ __forceinline__ unsigned short f2b(float f) {   // f32 -> bf16 RNE
    unsigned u = __builtin_bit_cast(unsigned, f);
    return (unsigned short)((u + 0x7fffu + ((u >> 16) & 1u)) >> 16);
}
__device__ __forceinline__ float b2f(unsigned short s) {
    return __builtin_bit_cast(float, (unsigned)s << 16);
}
__device__ __forceinline__ unsigned pk2(float lo, float hi) {
    return (unsigned)f2b(lo) | ((unsigned)f2b(hi) << 16);
}
__device__ __forceinline__ float blo(unsigned u) { return __builtin_bit_cast(float, u << 16); }
__device__ __forceinline__ float bhi(unsigned u) { return __builtin_bit_cast(float, u & 0xffff0000u); }

__global__ __launch_bounds__(256) void k_hist(const int* __restrict__ ei, int* __restrict__ cnt) {
    int e = blockIdx.x * 256 + threadIdx.x;
    if (e < NE) atomicAdd(&cnt[ei[NE + e]], 1);
}

__global__ __launch_bounds__(1024) void k_scan1(const int* __restrict__ cnt, int* __restrict__ rowptr,
                                                int* __restrict__ bsum) {
    __shared__ int wsum[16];
    int t = threadIdx.x, b = blockIdx.x;
    int idx = b * 1024 + t;
    int v = (idx < NN) ? cnt[idx] : 0;
    int lane = t & 63, w = t >> 6;
    int val = v;
    #pragma unroll
    for (int off = 1; off < 64; off <<= 1) { int u = __shfl_up(val, off); if (lane >= off) val += u; }
    if (lane == 63) wsum[w] = val;
    __syncthreads();
    if (w == 0) {
        int x = (lane < 16) ? wsum[lane] : 0;
        #pragma unroll
        for (int off = 1; off < 16; off <<= 1) { int u = __shfl_up(x, off); if (lane >= off) x += u; }
        if (lane < 16) wsum[lane] = x;
    }
    __syncthreads();
    int excl = val - v + (w > 0 ? wsum[w - 1] : 0);
    if (idx < NN) rowptr[idx] = excl;
    if (t == 1023) bsum[b] = wsum[15];
}

__global__ __launch_bounds__(64) void k_scan2(int* __restrict__ bsum, int* __restrict__ rowptr) {
    int lane = threadIdx.x;
    int v = (lane < 40) ? bsum[lane] : 0;
    int val = v;
    #pragma unroll
    for (int off = 1; off < 64; off <<= 1) { int u = __shfl_up(val, off); if (lane >= off) val += u; }
    if (lane < 40) bsum[lane] = val - v;
    if (lane == 0) rowptr[NN] = NE;
}

__global__ __launch_bounds__(1024) void k_scan3(int* __restrict__ rowptr, const int* __restrict__ bsum,
                                                int* __restrict__ fill) {
    int t = threadIdx.x, b = blockIdx.x;
    int idx = b * 1024 + t;
    if (idx < NN) {
        int r = rowptr[idx] + bsum[b];
        rowptr[idx] = r;
        fill[idx] = r;
    }
}

__global__ __launch_bounds__(256) void k_scatter(const int* __restrict__ ei, int* __restrict__ fill,
                                                 int* __restrict__ sorted) {
    int e = blockIdx.x * 256 + threadIdx.x;
    if (e < NE) {
        int src = ei[e], dst = ei[NE + e];
        int pos = atomicAdd(&fill[dst], 1);
        sorted[pos] = src;
    }
}

__global__ __launch_bounds__(256) void k_wprep1(const float* __restrict__ W1l, const float* __restrict__ W1r,
                                                unsigned short* __restrict__ w1b) {
    int i = blockIdx.x * 256 + threadIdx.x;      // < 32768
    int m = i >> 14, rc = i & 16383;
    const float* src = (m == 0) ? W1l : W1r;
    w1b[i] = f2b(src[rc]);
}

// x (f32) -> xb (bf16); ALSO zeroes fill[] and stats[] (replaces two hipMemsetAsync
// dispatches that cost ~43us each of pure launch/ramp overhead in the captured graph).
__global__ __launch_bounds__(256) void k_x2b(const float* __restrict__ x, unsigned short* __restrict__ xb,
                                             int* __restrict__ fill, float* __restrict__ stats) {
    int gid = blockIdx.x * 256 + threadIdx.x;    // < 640000
    if (gid < NN) fill[gid] = 0;
    if (gid >= 640000 - 256) stats[gid - (640000 - 256)] = 0.f;
    int i = gid * 8;
    float4 lo = *(const float4*)&x[i];
    float4 hi = *(const float4*)&x[i + 4];
    uint4 o;
    o.x = pk2(lo.x, lo.y); o.y = pk2(lo.z, lo.w);
    o.z = pk2(hi.x, hi.y); o.w = pk2(hi.z, hi.w);
    *(uint4*)&xb[i] = o;
}

__global__ __launch_bounds__(128) void k_bnfinal(float* __restrict__ stats, const float* __restrict__ gamma,
                                                 const float* __restrict__ beta) {
    int t = threadIdx.x;
    float mu  = stats[t] * (1.f / NN);
    float var = stats[F + t] * (1.f / NN) - mu * mu;
    float a = gamma[t] * rsqrtf(var + 1e-5f);
    stats[256 + t] = a;
    stats[384 + t] = beta[t] - mu * a;
}

__global__ __launch_bounds__(256) void k_wprep2(const float* __restrict__ W2l, const float* __restrict__ W2r,
                                                const float* __restrict__ b2l, float* __restrict__ stats,
                                                unsigned short* __restrict__ w2b) {
    int t = threadIdx.x;
    int o = t & 127;
    bool isL = t < 128;
    const float* W = isL ? W2l : W2r;
    unsigned short* dst = w2b + (isL ? 0 : 16384);
    float dot = 0.f;
    for (int k = 0; k < F; ++k) {
        float w = W[o * F + k];
        dst[o * F + k] = f2b(w * stats[256 + k]);
        dot = fmaf(stats[384 + k], w, dot);
    }
    if (isL) stats[128 + o] = dot;       // biasExtra (iff deg>0)
    else     stats[o] = b2l[o] + dot;    // bias2a (always)
}

// Gather (neighbor mean): one wave per node; quarter q, 4 rows in flight per lane.
__global__ __launch_bounds__(256) void k_agg(
    const unsigned short* __restrict__ featb,
    const int* __restrict__ rowptr, const int* __restrict__ sorted,
    unsigned short* __restrict__ aggm)
{
    int node = (blockIdx.x << 2) + (threadIdx.x >> 6);
    int lane = threadIdx.x & 63;
    int q = lane >> 4, li = lane & 15;
    int fo = li << 3;
    int e0 = rowptr[node], e1 = rowptr[node + 1];
    int deg = e1 - e0;
    float a0=0.f,a1=0.f,a2=0.f,a3=0.f,a4=0.f,a5=0.f,a6=0.f,a7=0.f;

#define ACC_EDGE(SRC) do { \
        uint4 u = *(const uint4*)&featb[(size_t)(SRC) * F + fo]; \
        a0 += blo(u.x); a1 += bhi(u.x); \
        a2 += blo(u.y); a3 += bhi(u.y); \
        a4 += blo(u.z); a5 += bhi(u.z); \
        a6 += blo(u.w); a7 += bhi(u.w); \
    } while (0)

    int e = e0;
    for (; e + 16 <= e1; e += 16) {
        int s0 = sorted[e + q];
        int s1 = sorted[e + 4 + q];
        int s2 = sorted[e + 8 + q];
        int s3 = sorted[e + 12 + q];
        ACC_EDGE(s0); ACC_EDGE(s1); ACC_EDGE(s2); ACC_EDGE(s3);
    }
    for (; e + 4 <= e1; e += 4) {
        int s0 = sorted[e + q];
        ACC_EDGE(s0);
    }
    if (e < e1 && q < (e1 - e)) {
        int s0 = sorted[e + q];
        ACC_EDGE(s0);
    }
#undef ACC_EDGE

    #pragma unroll
    for (int m = 16; m <= 32; m <<= 1) {
        a0 += __shfl_xor(a0, m); a1 += __shfl_xor(a1, m);
        a2 += __shfl_xor(a2, m); a3 += __shfl_xor(a3, m);
        a4 += __shfl_xor(a4, m); a5 += __shfl_xor(a5, m);
        a6 += __shfl_xor(a6, m); a7 += __shfl_xor(a7, m);
    }

    if (q == 0) {
        float inv = 1.f / (float)(deg > 1 ? deg : 1);
        uint4 o;
        o.x = pk2(a0 * inv, a1 * inv);
        o.y = pk2(a2 * inv, a3 * inv);
        o.z = pk2(a4 * inv, a5 * inv);
        o.w = pk2(a6 * inv, a7 * inv);
        *(uint4*)&aggm[(size_t)node * F + fo] = o;
    }
}

// Persistent MFMA dual GEMM (r12-proven). 250 blocks; weights staged ONCE per block via
// async global_load_lds (linear LDS dest + pre-swizzled source), 5 tiles with A dbuf.
template<int CONV2>
__global__ __launch_bounds__(256) void k_gemm(
    const unsigned short* __restrict__ aggm,
    const unsigned short* __restrict__ selfb,   // conv1: xb, conv2: h1
    const unsigned short* __restrict__ wb,      // wl | wr bf16 [out][k], 64KB
    const float* __restrict__ bias1,
    const float* __restrict__ biasA, const float* __restrict__ biasE,
    const int* __restrict__ rowptr,
    unsigned short* __restrict__ h1, float* __restrict__ stats,
    const float* __restrict__ Wfc, const float* __restrict__ bfc,
    float* __restrict__ out)
{
    __shared__ __align__(16) char smem[SM_TOT];
    int t = threadIdx.x;
    int nb0 = blockIdx.x * (NT * TPB);
    int w = t >> 6, lane = t & 63;
    int li = lane & 15, kg = lane >> 4;
    float (*sC)[132] = (float(*)[132])(smem + SM_C);

    // ---- weight stage (once): 16 async 1KB calls per wave ----
    {
        const char* wsrc = (const char*)wb;
        #pragma unroll
        for (int i = 0; i < 16; ++i) {
            unsigned Lb = (unsigned)(w * 16384 + i * 1024);
            unsigned s = Lb + (unsigned)lane * 16u;
            unsigned g = s ^ (((s >> 8) & 7u) << 4);
            GLL(wsrc + g, smem + Lb);
        }
    }

#define STAGE_A(TI, BUF) { \
        size_t rowb = (size_t)(nb0 + (TI) * NT) * 256u; \
        const char* asrc_ = (const char*)aggm + rowb; \
        const char* ssrc_ = (const char*)selfb + rowb; \
        _Pragma("unroll") \
        for (int i_ = 0; i_ < 2; ++i_) { \
            unsigned q_ = (unsigned)(w * 2048 + i_ * 1024); \
            unsigned s_ = q_ + (unsigned)lane * 16u; \
            unsigned g_ = s_ ^ (((s_ >> 8) & 7u) << 4); \
            GLL(asrc_ + g_, smem + (BUF) + q_); \
            GLL(ssrc_ + g_, smem + (BUF) + 8192u + q_); \
        } }

    STAGE_A(0, SM_A0)
    __syncthreads();   // vmcnt drained before barrier: weights + tile0 in LDS

    float sAcc = 0.f, s2Acc = 0.f;   // conv1 BN stats, accumulated across tiles
    int cp = w;
    unsigned swz = ((unsigned)(li & 7) << 4);

    for (int tt = 0; tt < TPB; ++tt) {
        unsigned bufC = (tt & 1) ? SM_A1 : SM_A0;
        unsigned bufN = (tt & 1) ? SM_A0 : SM_A1;
        if (tt + 1 < TPB) STAGE_A(tt + 1, bufN)   // async, lands by next barrier

        int nb = nb0 + tt * NT;

        // ---- MFMA: wave cp -> cols [cp*32, cp*32+32), rows 0..31 ----
        f32x4 acc00 = {0.f,0.f,0.f,0.f}, acc01 = {0.f,0.f,0.f,0.f};
        f32x4 acc10 = {0.f,0.f,0.f,0.f}, acc11 = {0.f,0.f,0.f,0.f};
        #pragma unroll
        for (int path = 0; path < 2; ++path) {
            unsigned aBase = bufC + (path ? 8192u : 0u);
            unsigned bBase = path ? 32768u : 0u;
            #pragma unroll
            for (int kc = 0; kc < 4; ++kc) {
                unsigned koff = (unsigned)(kg * 16 + kc * 64);
                bf16x8 a0 = *(const bf16x8*)(smem + aBase + (((unsigned)li * 256u + koff) ^ swz));
                bf16x8 a1 = *(const bf16x8*)(smem + aBase + (((unsigned)(16 + li) * 256u + koff) ^ swz));
                bf16x8 b0 = *(const bf16x8*)(smem + bBase + (((unsigned)(cp * 32 + li) * 256u + koff) ^ swz));
                bf16x8 b1 = *(const bf16x8*)(smem + bBase + (((unsigned)(cp * 32 + 16 + li) * 256u + koff) ^ swz));
                acc00 = __builtin_amdgcn_mfma_f32_16x16x32_bf16(a0, b0, acc00, 0, 0, 0);
                acc01 = __builtin_amdgcn_mfma_f32_16x16x32_bf16(a0, b1, acc01, 0, 0, 0);
                acc10 = __builtin_amdgcn_mfma_f32_16x16x32_bf16(a1, b0, acc10, 0, 0, 0);
                acc11 = __builtin_amdgcn_mfma_f32_16x16x32_bf16(a1, b1, acc11, 0, 0, 0);
            }
        }
        __syncthreads();   // B1: compute-cur done; next-tile async loads drained

        // ---- C -> sC (layout r6/r11-verified: reg r -> row kg*4+r, col li) ----
        #pragma unroll
        for (int r = 0; r < 4; ++r) {
            sC[kg * 4 + r][cp * 32 + li]           = acc00[r];
            sC[kg * 4 + r][cp * 32 + 16 + li]      = acc01[r];
            sC[16 + kg * 4 + r][cp * 32 + li]      = acc10[r];
            sC[16 + kg * 4 + r][cp * 32 + 16 + li] = acc11[r];
        }
        __syncthreads();   // B2

        // ---- bias + row L2 norm: thread -> row t>>3, cols (t&7)*16..+16 ----
        int row = t >> 3, cb = (t & 7) * 16;
        int node = nb + row;
        float v[16];
        float ss = 0.f;
        if constexpr (!CONV2) {
            #pragma unroll
            for (int j = 0; j < 16; ++j) {
                v[j] = sC[row][cb + j] + bias1[cb + j];
                ss = fmaf(v[j], v[j], ss);
            }
        } else {
            float flag = (rowptr[node + 1] > rowptr[node]) ? 1.f : 0.f;
            #pragma unroll
            for (int j = 0; j < 16; ++j) {
                v[j] = sC[row][cb + j] + biasA[cb + j] + flag * biasE[cb + j];
                ss = fmaf(v[j], v[j], ss);
            }
        }
        ss += __shfl_xor(ss, 1); ss += __shfl_xor(ss, 2); ss += __shfl_xor(ss, 4);
        float sc = 1.f / fmaxf(sqrtf(ss), 1e-12f);

        if constexpr (!CONV2) {
            #pragma unroll
            for (int j = 0; j < 16; ++j) {
                v[j] = fmaxf(v[j] * sc, 0.f);       // normalize then relu
                sC[row][cb + j] = v[j];             // f32 for BN stats
            }
            uint4 p0, p1;
            p0.x = pk2(v[0], v[1]);   p0.y = pk2(v[2], v[3]);
            p0.z = pk2(v[4], v[5]);   p0.w = pk2(v[6], v[7]);
            p1.x = pk2(v[8], v[9]);   p1.y = pk2(v[10], v[11]);
            p1.z = pk2(v[12], v[13]); p1.w = pk2(v[14], v[15]);
            *(uint4*)&h1[(size_t)node * F + cb]     = p0;
            *(uint4*)&h1[(size_t)node * F + cb + 8] = p1;
            __syncthreads();   // B3: normalized sC visible for stats
            if (t < F) {
                #pragma unroll
                for (int r = 0; r < NT; ++r) {
                    float h = sC[r][t];
                    sAcc += h; s2Acc = fmaf(h, h, s2Acc);
                }
            }
        } else {
            #pragma unroll
            for (int j = 0; j < 16; ++j) sC[row][cb + j] = v[j] * sc;
            __syncthreads();   // B3: normalized sC visible for fc
            #pragma unroll
            for (int pp = 0; pp < 2; ++pp) {
                int p = t + pp * 256;
                int n = p >> 4, c = p & 15;
                float s = bfc[c];
                for (int o = 0; o < F; o += 4) {
                    float4 h4 = *(const float4*)&sC[n][o];
                    float4 w4 = *(const float4*)&Wfc[c * F + o];
                    s += h4.x * w4.x + h4.y * w4.y + h4.z * w4.z + h4.w * w4.w;
                }
                out[(size_t)(nb + n) * NC + c] = s;
            }
        }
        // next iteration's B1 protects sC reuse and buffer swap
    }

    if constexpr (!CONV2) {
        if (t < F) {
            atomicAdd(&stats[t], sAcc);
            atomicAdd(&stats[F + t], s2Acc);
        }
    }
#undef STAGE_A
}

extern "C" void kernel_launch(void* const* d_in, const int* in_sizes, int n_in,
                              void* d_out, int out_size, void* d_ws, size_t ws_size,
                              hipStream_t stream) {
    const float* x     = (const float*)d_in[0];
    const int*   ei    = (const int*)d_in[1];
    const float* W1l   = (const float*)d_in[2];
    const float* b1l   = (const float*)d_in[3];
    const float* W1r   = (const float*)d_in[4];
    const float* gamma = (const float*)d_in[5];
    const float* beta  = (const float*)d_in[6];
    const float* W2l   = (const float*)d_in[7];
    const float* b2l   = (const float*)d_in[8];
    const float* W2r   = (const float*)d_in[9];
    const float* Wfc   = (const float*)d_in[10];
    const float* bfc   = (const float*)d_in[11];

    char* ws = (char*)d_ws;
    int*            rowptr = (int*)(ws + OFF_ROWPTR);
    int*            fill   = (int*)(ws + OFF_FILL);
    int*            bsum   = (int*)(ws + OFF_BSUM);
    int*            sorted = (int*)(ws + OFF_SORTED);
    float*          stats  = (float*)(ws + OFF_STATS);
    unsigned short* w1b    = (unsigned short*)(ws + OFF_W1B);
    unsigned short* w2b    = (unsigned short*)(ws + OFF_W2B);
    unsigned short* xb     = (unsigned short*)(ws + OFF_XB);   // xb then h1 (same rows)
    unsigned short* aggm   = (unsigned short*)(ws + OFF_AGGM);
    float*          out    = (float*)d_out;

    k_x2b<<<NN * F / (256 * 8), 256, 0, stream>>>(x, xb, fill, stats);  // also zeroes fill+stats
    k_wprep1<<<128, 256, 0, stream>>>(W1l, W1r, w1b);
    k_hist<<<(NE + 255) / 256, 256, 0, stream>>>(ei, fill);
    k_scan1<<<40, 1024, 0, stream>>>(fill, rowptr, bsum);
    k_scan2<<<1, 64, 0, stream>>>(bsum, rowptr);
    k_scan3<<<40, 1024, 0, stream>>>(rowptr, bsum, fill);
    k_scatter<<<(NE + 255) / 256, 256, 0, stream>>>(ei, fill, sorted);

    // conv1
    k_agg<<<NN / 4, 256, 0, stream>>>(xb, rowptr, sorted, aggm);
    k_gemm<0><<<NN / (NT * TPB), 256, 0, stream>>>(aggm, xb, w1b, b1l, nullptr, nullptr,
                                                   rowptr, xb, stats, nullptr, nullptr, nullptr);
    k_bnfinal<<<1, 128, 0, stream>>>(stats, gamma, beta);
    k_wprep2<<<1, 256, 0, stream>>>(W2l, W2r, b2l, stats, w2b);

    // conv2 (+ fused fc); h1 lives in xb buffer
    k_agg<<<NN / 4, 256, 0, stream>>>(xb, rowptr, sorted, aggm);
    k_gemm<1><<<NN / (NT * TPB), 256, 0, stream>>>(aggm, xb, w2b, nullptr, stats, stats + 128,
                                                   rowptr, nullptr, nullptr, Wfc, bfc, out);
}

// Round 14
// 179.508 us; speedup vs baseline: 5.7613x; 1.0336x over previous
//
#include <hip/hip_runtime.h>

#define NN 40000
#define NE 640000
#define F 128
#define NC 16
#define NT 32    // nodes per tile
#define TPB 5    // tiles per persistent block (250 blocks x 5 x 32 = 40000)

typedef __attribute__((ext_vector_type(8))) short bf16x8;
typedef __attribute__((ext_vector_type(4))) float f32x4;

// ws layout (bytes); total 23501312 < proven 23632384
#define OFF_ROWPTR 0u
#define OFF_FILL   163968u
#define OFF_BSUM   327936u
#define OFF_SORTED 328192u
#define OFF_STATS  2888192u    // 512 f32: [sum|bias2a][sumsq|biasExtra][bn_a][bn_b]
#define OFF_W1B    2890240u    // w1l | w1r bf16 [out][k] (64 KB)
#define OFF_W2B    2955776u    // w2l | w2r bf16 [out][k], BN-scaled (64 KB)
#define OFF_XB     3021312u    // NN*F bf16: xb, then h1 overwrites same rows
#define OFF_AGGM   13261312u   // NN*F bf16

// LDS regions (k_gemm)
#define SM_W   0u        // weights 64 KB (swizzled image)
#define SM_A0  65536u    // A dbuf 0: agg 8K | self 8K
#define SM_A1  81920u    // A dbuf 1
#define SM_C   98304u    // sC [32][132] f32 = 16896 B
#define SM_TOT 115200u

#define GLL(gsrc, ldst) \
    __builtin_amdgcn_global_load_lds((const __attribute__((address_space(1))) void*)(gsrc), \
        (__attribute__((address_space(3))) void*)(ldst), 16, 0, 0)

__device__ __forceinline__ unsigned short f2b(float f) {   // f32 -> bf16 RNE
    unsigned u = __builtin_bit_cast(unsigned, f);
    return (unsigned short)((u + 0x7fffu + ((u >> 16) & 1u)) >> 16);
}
__device__ __forceinline__ float b2f(unsigned short s) {
    return __builtin_bit_cast(float, (unsigned)s << 16);
}
__device__ __forceinline__ unsigned pk2(float lo, float hi) {
    return (unsigned)f2b(lo) | ((unsigned)f2b(hi) << 16);
}
__device__ __forceinline__ float blo(unsigned u) { return __builtin_bit_cast(float, u << 16); }
__device__ __forceinline__ float bhi(unsigned u) { return __builtin_bit_cast(float, u & 0xffff0000u); }

// Fused prep: x->bf16 (8 elems/thread), W1 -> bf16, zero fill+stats.
// (All index-disjoint work; replaces 3 dispatches.)
__global__ __launch_bounds__(256) void k_prep(const float* __restrict__ x, unsigned short* __restrict__ xb,
                                              const float* __restrict__ W1l, const float* __restrict__ W1r,
                                              unsigned short* __restrict__ w1b,
                                              int* __restrict__ fill, float* __restrict__ stats) {
    int gid = blockIdx.x * 256 + threadIdx.x;    // < 640000
    if (gid < NN) fill[gid] = 0;
    if (gid < 256) stats[gid] = 0.f;
    if (gid < 32768) {
        int m = gid >> 14, rc = gid & 16383;
        const float* src = m ? W1r : W1l;
        w1b[gid] = f2b(src[rc]);
    }
    int i = gid * 8;
    float4 lo = *(const float4*)&x[i];
    float4 hi = *(const float4*)&x[i + 4];
    uint4 o;
    o.x = pk2(lo.x, lo.y); o.y = pk2(lo.z, lo.w);
    o.z = pk2(hi.x, hi.y); o.w = pk2(hi.z, hi.w);
    *(uint4*)&xb[i] = o;
}

__global__ __launch_bounds__(256) void k_hist(const int* __restrict__ ei, int* __restrict__ cnt) {
    int e = blockIdx.x * 256 + threadIdx.x;
    if (e < NE) atomicAdd(&cnt[ei[NE + e]], 1);
}

__global__ __launch_bounds__(1024) void k_scan1(const int* __restrict__ cnt, int* __restrict__ rowptr,
                                                int* __restrict__ bsum) {
    __shared__ int wsum[16];
    int t = threadIdx.x, b = blockIdx.x;
    int idx = b * 1024 + t;
    int v = (idx < NN) ? cnt[idx] : 0;
    int lane = t & 63, w = t >> 6;
    int val = v;
    #pragma unroll
    for (int off = 1; off < 64; off <<= 1) { int u = __shfl_up(val, off); if (lane >= off) val += u; }
    if (lane == 63) wsum[w] = val;
    __syncthreads();
    if (w == 0) {
        int x = (lane < 16) ? wsum[lane] : 0;
        #pragma unroll
        for (int off = 1; off < 16; off <<= 1) { int u = __shfl_up(x, off); if (lane >= off) x += u; }
        if (lane < 16) wsum[lane] = x;
    }
    __syncthreads();
    int excl = val - v + (w > 0 ? wsum[w - 1] : 0);
    if (idx < NN) rowptr[idx] = excl;
    if (t == 1023) bsum[b] = wsum[15];
}

// scan2 folded in: every wave redundantly exclusive-scans the 40 block sums (1 shuffle ladder),
// picks entry b; then adds to local-exclusive rowptr and mirrors into fill.
__global__ __launch_bounds__(1024) void k_scan3(int* __restrict__ rowptr, const int* __restrict__ bsum,
                                                int* __restrict__ fill) {
    int t = threadIdx.x, b = blockIdx.x;
    int lane = t & 63;
    int v = (lane < 40) ? bsum[lane] : 0;
    int val = v;
    #pragma unroll
    for (int off = 1; off < 64; off <<= 1) { int u = __shfl_up(val, off); if (lane >= off) val += u; }
    int base = __shfl(val - v, b);
    int idx = b * 1024 + t;
    if (idx < NN) {
        int r = rowptr[idx] + base;
        rowptr[idx] = r;
        fill[idx] = r;
    }
    if (b == 0 && t == 0) rowptr[NN] = NE;
}

__global__ __launch_bounds__(256) void k_scatter(const int* __restrict__ ei, int* __restrict__ fill,
                                                 int* __restrict__ sorted) {
    int e = blockIdx.x * 256 + threadIdx.x;
    if (e < NE) {
        int src = ei[e], dst = ei[NE + e];
        int pos = atomicAdd(&fill[dst], 1);
        sorted[pos] = src;
    }
}

// bnfinal folded in: first 128 threads compute BN affine from the (kernel-boundary-visible)
// stats sums, then the weight fold proceeds after the barrier.
__global__ __launch_bounds__(256) void k_wprep2(const float* __restrict__ W2l, const float* __restrict__ W2r,
                                                const float* __restrict__ b2l,
                                                const float* __restrict__ gamma, const float* __restrict__ beta,
                                                float* __restrict__ stats,
                                                unsigned short* __restrict__ w2b) {
    int t = threadIdx.x;
    if (t < 128) {
        float mu  = stats[t] * (1.f / NN);
        float var = stats[F + t] * (1.f / NN) - mu * mu;
        float a = gamma[t] * rsqrtf(var + 1e-5f);
        stats[256 + t] = a;
        stats[384 + t] = beta[t] - mu * a;
    }
    __syncthreads();
    int o = t & 127;
    bool isL = t < 128;
    const float* W = isL ? W2l : W2r;
    unsigned short* dst = w2b + (isL ? 0 : 16384);
    float dot = 0.f;
    for (int k = 0; k < F; ++k) {
        float w = W[o * F + k];
        dst[o * F + k] = f2b(w * stats[256 + k]);
        dot = fmaf(stats[384 + k], w, dot);
    }
    if (isL) stats[128 + o] = dot;       // biasExtra (iff deg>0)
    else     stats[o] = b2l[o] + dot;    // bias2a (always)
}

// Gather (neighbor mean): one wave per node; quarter q, up to 4 rows in flight per lane.
__global__ __launch_bounds__(256) void k_agg(
    const unsigned short* __restrict__ featb,
    const int* __restrict__ rowptr, const int* __restrict__ sorted,
    unsigned short* __restrict__ aggm)
{
    int node = (blockIdx.x << 2) + (threadIdx.x >> 6);
    int lane = threadIdx.x & 63;
    int q = lane >> 4, li = lane & 15;
    int fo = li << 3;
    int e0 = rowptr[node], e1 = rowptr[node + 1];
    int deg = e1 - e0;
    float a0=0.f,a1=0.f,a2=0.f,a3=0.f,a4=0.f,a5=0.f,a6=0.f,a7=0.f;

#define ACC_EDGE(SRC) do { \
        uint4 u = *(const uint4*)&featb[(size_t)(SRC) * F + fo]; \
        a0 += blo(u.x); a1 += bhi(u.x); \
        a2 += blo(u.y); a3 += bhi(u.y); \
        a4 += blo(u.z); a5 += bhi(u.z); \
        a6 += blo(u.w); a7 += bhi(u.w); \
    } while (0)

    int e = e0;
    for (; e + 16 <= e1; e += 16) {
        int s0 = sorted[e + q];
        int s1 = sorted[e + 4 + q];
        int s2 = sorted[e + 8 + q];
        int s3 = sorted[e + 12 + q];
        ACC_EDGE(s0); ACC_EDGE(s1); ACC_EDGE(s2); ACC_EDGE(s3);
    }
    for (; e + 8 <= e1; e += 8) {
        int s0 = sorted[e + q];
        int s1 = sorted[e + 4 + q];
        ACC_EDGE(s0); ACC_EDGE(s1);
    }
    for (; e + 4 <= e1; e += 4) {
        int s0 = sorted[e + q];
        ACC_EDGE(s0);
    }
    if (e < e1 && q < (e1 - e)) {
        int s0 = sorted[e + q];
        ACC_EDGE(s0);
    }
#undef ACC_EDGE

    #pragma unroll
    for (int m = 16; m <= 32; m <<= 1) {
        a0 += __shfl_xor(a0, m); a1 += __shfl_xor(a1, m);
        a2 += __shfl_xor(a2, m); a3 += __shfl_xor(a3, m);
        a4 += __shfl_xor(a4, m); a5 += __shfl_xor(a5, m);
        a6 += __shfl_xor(a6, m); a7 += __shfl_xor(a7, m);
    }

    if (q == 0) {
        float inv = 1.f / (float)(deg > 1 ? deg : 1);
        uint4 o;
        o.x = pk2(a0 * inv, a1 * inv);
        o.y = pk2(a2 * inv, a3 * inv);
        o.z = pk2(a4 * inv, a5 * inv);
        o.w = pk2(a6 * inv, a7 * inv);
        *(uint4*)&aggm[(size_t)node * F + fo] = o;
    }
}

// Persistent MFMA dual GEMM (r12-proven). 250 blocks; weights staged ONCE per block via
// async global_load_lds (linear LDS dest + pre-swizzled source), 5 tiles with A dbuf.
template<int CONV2>
__global__ __launch_bounds__(256) void k_gemm(
    const unsigned short* __restrict__ aggm,
    const unsigned short* __restrict__ selfb,   // conv1: xb, conv2: h1
    const unsigned short* __restrict__ wb,      // wl | wr bf16 [out][k], 64KB
    const float* __restrict__ bias1,
    const float* __restrict__ biasA, const float* __restrict__ biasE,
    const int* __restrict__ rowptr,
    unsigned short* __restrict__ h1, float* __restrict__ stats,
    const float* __restrict__ Wfc, const float* __restrict__ bfc,
    float* __restrict__ out)
{
    __shared__ __align__(16) char smem[SM_TOT];
    int t = threadIdx.x;
    int nb0 = blockIdx.x * (NT * TPB);
    int w = t >> 6, lane = t & 63;
    int li = lane & 15, kg = lane >> 4;
    float (*sC)[132] = (float(*)[132])(smem + SM_C);

    // ---- weight stage (once): 16 async 1KB calls per wave ----
    {
        const char* wsrc = (const char*)wb;
        #pragma unroll
        for (int i = 0; i < 16; ++i) {
            unsigned Lb = (unsigned)(w * 16384 + i * 1024);
            unsigned s = Lb + (unsigned)lane * 16u;
            unsigned g = s ^ (((s >> 8) & 7u) << 4);
            GLL(wsrc + g, smem + Lb);
        }
    }

#define STAGE_A(TI, BUF) { \
        size_t rowb = (size_t)(nb0 + (TI) * NT) * 256u; \
        const char* asrc_ = (const char*)aggm + rowb; \
        const char* ssrc_ = (const char*)selfb + rowb; \
        _Pragma("unroll") \
        for (int i_ = 0; i_ < 2; ++i_) { \
            unsigned q_ = (unsigned)(w * 2048 + i_ * 1024); \
            unsigned s_ = q_ + (unsigned)lane * 16u; \
            unsigned g_ = s_ ^ (((s_ >> 8) & 7u) << 4); \
            GLL(asrc_ + g_, smem + (BUF) + q_); \
            GLL(ssrc_ + g_, smem + (BUF) + 8192u + q_); \
        } }

    STAGE_A(0, SM_A0)
    __syncthreads();   // vmcnt drained before barrier: weights + tile0 in LDS

    float sAcc = 0.f, s2Acc = 0.f;   // conv1 BN stats, accumulated across tiles
    int cp = w;
    unsigned swz = ((unsigned)(li & 7) << 4);

    for (int tt = 0; tt < TPB; ++tt) {
        unsigned bufC = (tt & 1) ? SM_A1 : SM_A0;
        unsigned bufN = (tt & 1) ? SM_A0 : SM_A1;
        if (tt + 1 < TPB) STAGE_A(tt + 1, bufN)   // async, lands by next barrier

        int nb = nb0 + tt * NT;

        // ---- MFMA: wave cp -> cols [cp*32, cp*32+32), rows 0..31 ----
        f32x4 acc00 = {0.f,0.f,0.f,0.f}, acc01 = {0.f,0.f,0.f,0.f};
        f32x4 acc10 = {0.f,0.f,0.f,0.f}, acc11 = {0.f,0.f,0.f,0.f};
        #pragma unroll
        for (int path = 0; path < 2; ++path) {
            unsigned aBase = bufC + (path ? 8192u : 0u);
            unsigned bBase = path ? 32768u : 0u;
            #pragma unroll
            for (int kc = 0; kc < 4; ++kc) {
                unsigned koff = (unsigned)(kg * 16 + kc * 64);
                bf16x8 a0 = *(const bf16x8*)(smem + aBase + (((unsigned)li * 256u + koff) ^ swz));
                bf16x8 a1 = *(const bf16x8*)(smem + aBase + (((unsigned)(16 + li) * 256u + koff) ^ swz));
                bf16x8 b0 = *(const bf16x8*)(smem + bBase + (((unsigned)(cp * 32 + li) * 256u + koff) ^ swz));
                bf16x8 b1 = *(const bf16x8*)(smem + bBase + (((unsigned)(cp * 32 + 16 + li) * 256u + koff) ^ swz));
                acc00 = __builtin_amdgcn_mfma_f32_16x16x32_bf16(a0, b0, acc00, 0, 0, 0);
                acc01 = __builtin_amdgcn_mfma_f32_16x16x32_bf16(a0, b1, acc01, 0, 0, 0);
                acc10 = __builtin_amdgcn_mfma_f32_16x16x32_bf16(a1, b0, acc10, 0, 0, 0);
                acc11 = __builtin_amdgcn_mfma_f32_16x16x32_bf16(a1, b1, acc11, 0, 0, 0);
            }
        }
        __syncthreads();   // B1: compute-cur done; next-tile async loads drained

        // ---- C -> sC (layout r6/r11-verified: reg r -> row kg*4+r, col li) ----
        #pragma unroll
        for (int r = 0; r < 4; ++r) {
            sC[kg * 4 + r][cp * 32 + li]           = acc00[r];
            sC[kg * 4 + r][cp * 32 + 16 + li]      = acc01[r];
            sC[16 + kg * 4 + r][cp * 32 + li]      = acc10[r];
            sC[16 + kg * 4 + r][cp * 32 + 16 + li] = acc11[r];
        }
        __syncthreads();   // B2

        // ---- bias + row L2 norm: thread -> row t>>3, cols (t&7)*16..+16 ----
        int row = t >> 3, cb = (t & 7) * 16;
        int node = nb + row;
        float v[16];
        float ss = 0.f;
        if constexpr (!CONV2) {
            #pragma unroll
            for (int j = 0; j < 16; ++j) {
                v[j] = sC[row][cb + j] + bias1[cb + j];
                ss = fmaf(v[j], v[j], ss);
            }
        } else {
            float flag = (rowptr[node + 1] > rowptr[node]) ? 1.f : 0.f;
            #pragma unroll
            for (int j = 0; j < 16; ++j) {
                v[j] = sC[row][cb + j] + biasA[cb + j] + flag * biasE[cb + j];
                ss = fmaf(v[j], v[j], ss);
            }
        }
        ss += __shfl_xor(ss, 1); ss += __shfl_xor(ss, 2); ss += __shfl_xor(ss, 4);
        float sc = 1.f / fmaxf(sqrtf(ss), 1e-12f);

        if constexpr (!CONV2) {
            #pragma unroll
            for (int j = 0; j < 16; ++j) {
                v[j] = fmaxf(v[j] * sc, 0.f);       // normalize then relu
                sC[row][cb + j] = v[j];             // f32 for BN stats
            }
            uint4 p0, p1;
            p0.x = pk2(v[0], v[1]);   p0.y = pk2(v[2], v[3]);
            p0.z = pk2(v[4], v[5]);   p0.w = pk2(v[6], v[7]);
            p1.x = pk2(v[8], v[9]);   p1.y = pk2(v[10], v[11]);
            p1.z = pk2(v[12], v[13]); p1.w = pk2(v[14], v[15]);
            *(uint4*)&h1[(size_t)node * F + cb]     = p0;
            *(uint4*)&h1[(size_t)node * F + cb + 8] = p1;
            __syncthreads();   // B3: normalized sC visible for stats
            if (t < F) {
                #pragma unroll
                for (int r = 0; r < NT; ++r) {
                    float h = sC[r][t];
                    sAcc += h; s2Acc = fmaf(h, h, s2Acc);
                }
            }
        } else {
            #pragma unroll
            for (int j = 0; j < 16; ++j) sC[row][cb + j] = v[j] * sc;
            __syncthreads();   // B3: normalized sC visible for fc
            #pragma unroll
            for (int pp = 0; pp < 2; ++pp) {
                int p = t + pp * 256;
                int n = p >> 4, c = p & 15;
                float s = bfc[c];
                for (int o = 0; o < F; o += 4) {
                    float4 h4 = *(const float4*)&sC[n][o];
                    float4 w4 = *(const float4*)&Wfc[c * F + o];
                    s += h4.x * w4.x + h4.y * w4.y + h4.z * w4.z + h4.w * w4.w;
                }
                out[(size_t)(nb + n) * NC + c] = s;
            }
        }
        // next iteration's B1 protects sC reuse and buffer swap
    }

    if constexpr (!CONV2) {
        if (t < F) {
            atomicAdd(&stats[t], sAcc);
            atomicAdd(&stats[F + t], s2Acc);
        }
    }
#undef STAGE_A
}

extern "C" void kernel_launch(void* const* d_in, const int* in_sizes, int n_in,
                              void* d_out, int out_size, void* d_ws, size_t ws_size,
                              hipStream_t stream) {
    const float* x     = (const float*)d_in[0];
    const int*   ei    = (const int*)d_in[1];
    const float* W1l   = (const float*)d_in[2];
    const float* b1l   = (const float*)d_in[3];
    const float* W1r   = (const float*)d_in[4];
    const float* gamma = (const float*)d_in[5];
    const float* beta  = (const float*)d_in[6];
    const float* W2l   = (const float*)d_in[7];
    const float* b2l   = (const float*)d_in[8];
    const float* W2r   = (const float*)d_in[9];
    const float* Wfc   = (const float*)d_in[10];
    const float* bfc   = (const float*)d_in[11];

    char* ws = (char*)d_ws;
    int*            rowptr = (int*)(ws + OFF_ROWPTR);
    int*            fill   = (int*)(ws + OFF_FILL);
    int*            bsum   = (int*)(ws + OFF_BSUM);
    int*            sorted = (int*)(ws + OFF_SORTED);
    float*          stats  = (float*)(ws + OFF_STATS);
    unsigned short* w1b    = (unsigned short*)(ws + OFF_W1B);
    unsigned short* w2b    = (unsigned short*)(ws + OFF_W2B);
    unsigned short* xb     = (unsigned short*)(ws + OFF_XB);   // xb then h1 (same rows)
    unsigned short* aggm   = (unsigned short*)(ws + OFF_AGGM);
    float*          out    = (float*)d_out;

    k_prep<<<NN * F / (256 * 8), 256, 0, stream>>>(x, xb, W1l, W1r, w1b, fill, stats);
    k_hist<<<(NE + 255) / 256, 256, 0, stream>>>(ei, fill);
    k_scan1<<<40, 1024, 0, stream>>>(fill, rowptr, bsum);
    k_scan3<<<40, 1024, 0, stream>>>(rowptr, bsum, fill);
    k_scatter<<<(NE + 255) / 256, 256, 0, stream>>>(ei, fill, sorted);

    // conv1
    k_agg<<<NN / 4, 256, 0, stream>>>(xb, rowptr, sorted, aggm);
    k_gemm<0><<<NN / (NT * TPB), 256, 0, stream>>>(aggm, xb, w1b, b1l, nullptr, nullptr,
                                                   rowptr, xb, stats, nullptr, nullptr, nullptr);
    k_wprep2<<<1, 256, 0, stream>>>(W2l, W2r, b2l, gamma, beta, stats, w2b);

    // conv2 (+ fused fc); h1 lives in xb buffer
    k_agg<<<NN / 4, 256, 0, stream>>>(xb, rowptr, sorted, aggm);
    k_gemm<1><<<NN / (NT * TPB), 256, 0, stream>>>(aggm, xb, w2b, nullptr, stats, stats + 128,
                                                   rowptr, nullptr, nullptr, Wfc, bfc, out);
}

// Round 15
// 171.598 us; speedup vs baseline: 6.0269x; 1.0461x over previous
//
#include <hip/hip_runtime.h>

#define NN 40000
#define NE 640000
#define F 128
#define NC 16
#define NT 32    // nodes per tile
#define TPB 5    // tiles per persistent block (250 blocks x 5 x 32 = 40000)

typedef __attribute__((ext_vector_type(8))) short bf16x8;
typedef __attribute__((ext_vector_type(4))) float f32x4;

// ws layout (bytes); total 23501312 < proven 23632384
#define OFF_ROWPTR 0u
#define OFF_FILL   163968u     // NN ints; DEAD after k_scatter -> first 256 f32 reused as biasA/biasE
#define OFF_BSUM   327936u
#define OFF_SORTED 328192u
#define OFF_STATS  2888192u    // 512 f32: [sum][sumsq][..][..] (sums stay intact now)
#define OFF_W1B    2890240u    // w1l | w1r bf16 [out][k] (64 KB)
#define OFF_W2B    2955776u    // w2l | w2r bf16 [out][k], BN-scaled (64 KB)
#define OFF_XB     3021312u    // NN*F bf16: xb, then h1 overwrites same rows
#define OFF_AGGM   13261312u   // NN*F bf16

// LDS regions (k_gemm)
#define SM_W   0u        // weights 64 KB (swizzled image)
#define SM_A0  65536u    // A dbuf 0: agg 8K | self 8K
#define SM_A1  81920u    // A dbuf 1
#define SM_C   98304u    // sC [32][132] f32 = 16896 B
#define SM_TOT 115200u

#define GLL(gsrc, ldst) \
    __builtin_amdgcn_global_load_lds((const __attribute__((address_space(1))) void*)(gsrc), \
        (__attribute__((address_space(3))) void*)(ldst), 16, 0, 0)

__device__ __forceinline__ unsigned short f2b(float f) {   // f32 -> bf16 RNE
    unsigned u = __builtin_bit_cast(unsigned, f);
    return (unsigned short)((u + 0x7fffu + ((u >> 16) & 1u)) >> 16);
}
__device__ __forceinline__ float b2f(unsigned short s) {
    return __builtin_bit_cast(float, (unsigned)s << 16);
}
__device__ __forceinline__ unsigned pk2(float lo, float hi) {
    return (unsigned)f2b(lo) | ((unsigned)f2b(hi) << 16);
}
__device__ __forceinline__ float blo(unsigned u) { return __builtin_bit_cast(float, u << 16); }
__device__ __forceinline__ float bhi(unsigned u) { return __builtin_bit_cast(float, u & 0xffff0000u); }

// Fused prep: x->bf16 (8 elems/thread), W1 -> bf16, zero fill+stats.
__global__ __launch_bounds__(256) void k_prep(const float* __restrict__ x, unsigned short* __restrict__ xb,
                                              const float* __restrict__ W1l, const float* __restrict__ W1r,
                                              unsigned short* __restrict__ w1b,
                                              int* __restrict__ fill, float* __restrict__ stats) {
    int gid = blockIdx.x * 256 + threadIdx.x;    // < 640000
    if (gid < NN) fill[gid] = 0;
    if (gid < 256) stats[gid] = 0.f;
    if (gid < 32768) {
        int m = gid >> 14, rc = gid & 16383;
        const float* src = m ? W1r : W1l;
        w1b[gid] = f2b(src[rc]);
    }
    int i = gid * 8;
    float4 lo = *(const float4*)&x[i];
    float4 hi = *(const float4*)&x[i + 4];
    uint4 o;
    o.x = pk2(lo.x, lo.y); o.y = pk2(lo.z, lo.w);
    o.z = pk2(hi.x, hi.y); o.w = pk2(hi.z, hi.w);
    *(uint4*)&xb[i] = o;
}

__global__ __launch_bounds__(256) void k_hist(const int* __restrict__ ei, int* __restrict__ cnt) {
    int e = blockIdx.x * 256 + threadIdx.x;
    if (e < NE) atomicAdd(&cnt[ei[NE + e]], 1);
}

__global__ __launch_bounds__(1024) void k_scan1(const int* __restrict__ cnt, int* __restrict__ rowptr,
                                                int* __restrict__ bsum) {
    __shared__ int wsum[16];
    int t = threadIdx.x, b = blockIdx.x;
    int idx = b * 1024 + t;
    int v = (idx < NN) ? cnt[idx] : 0;
    int lane = t & 63, w = t >> 6;
    int val = v;
    #pragma unroll
    for (int off = 1; off < 64; off <<= 1) { int u = __shfl_up(val, off); if (lane >= off) val += u; }
    if (lane == 63) wsum[w] = val;
    __syncthreads();
    if (w == 0) {
        int x = (lane < 16) ? wsum[lane] : 0;
        #pragma unroll
        for (int off = 1; off < 16; off <<= 1) { int u = __shfl_up(x, off); if (lane >= off) x += u; }
        if (lane < 16) wsum[lane] = x;
    }
    __syncthreads();
    int excl = val - v + (w > 0 ? wsum[w - 1] : 0);
    if (idx < NN) rowptr[idx] = excl;
    if (t == 1023) bsum[b] = wsum[15];
}

// scan2 folded in: every wave redundantly exclusive-scans the 40 block sums.
__global__ __launch_bounds__(1024) void k_scan3(int* __restrict__ rowptr, const int* __restrict__ bsum,
                                                int* __restrict__ fill) {
    int t = threadIdx.x, b = blockIdx.x;
    int lane = t & 63;
    int v = (lane < 40) ? bsum[lane] : 0;
    int val = v;
    #pragma unroll
    for (int off = 1; off < 64; off <<= 1) { int u = __shfl_up(val, off); if (lane >= off) val += u; }
    int base = __shfl(val - v, b);
    int idx = b * 1024 + t;
    if (idx < NN) {
        int r = rowptr[idx] + base;
        rowptr[idx] = r;
        fill[idx] = r;
    }
    if (b == 0 && t == 0) rowptr[NN] = NE;
}

__global__ __launch_bounds__(256) void k_scatter(const int* __restrict__ ei, int* __restrict__ fill,
                                                 int* __restrict__ sorted) {
    int e = blockIdx.x * 256 + threadIdx.x;
    if (e < NE) {
        int src = ei[e], dst = ei[NE + e];
        int pos = atomicAdd(&fill[dst], 1);
        sorted[pos] = src;
    }
}

// Parallel BN-fold: 256 blocks x 128 threads; block = (side, output col o).
// BN affine recomputed per-thread from intact stats sums (cheap); dot reduced via
// shuffle + 2-slot LDS. Biases written to the dead fill region (biasA[0..127], biasE[128..255]).
__global__ __launch_bounds__(128) void k_wprep2(const float* __restrict__ W2l, const float* __restrict__ W2r,
                                                const float* __restrict__ b2l,
                                                const float* __restrict__ gamma, const float* __restrict__ beta,
                                                const float* __restrict__ stats,
                                                unsigned short* __restrict__ w2b,
                                                float* __restrict__ biasAE) {
    __shared__ float red[2];
    int b = blockIdx.x;
    int side = b >> 7, o = b & 127;   // side 0 = W2l (-> biasE), side 1 = W2r (-> biasA)
    int k = threadIdx.x;
    float mu  = stats[k] * (1.f / NN);
    float var = stats[F + k] * (1.f / NN) - mu * mu;
    float a = gamma[k] * rsqrtf(var + 1e-5f);
    float bb = beta[k] - mu * a;
    const float* W = side ? W2r : W2l;
    float w = W[o * F + k];
    w2b[(side ? 16384 : 0) + o * F + k] = f2b(w * a);
    float d = bb * w;
    #pragma unroll
    for (int off = 1; off < 64; off <<= 1) d += __shfl_xor(d, off);
    if ((k & 63) == 0) red[k >> 6] = d;
    __syncthreads();
    if (k == 0) {
        float dot = red[0] + red[1];
        if (side) biasAE[o] = b2l[o] + dot;        // bias2a (always applied)
        else      biasAE[128 + o] = dot;           // biasExtra (iff deg>0)
    }
}

// Gather (neighbor mean): one wave per node; quarter q, up to 4 rows in flight per lane.
__global__ __launch_bounds__(256) void k_agg(
    const unsigned short* __restrict__ featb,
    const int* __restrict__ rowptr, const int* __restrict__ sorted,
    unsigned short* __restrict__ aggm)
{
    int node = (blockIdx.x << 2) + (threadIdx.x >> 6);
    int lane = threadIdx.x & 63;
    int q = lane >> 4, li = lane & 15;
    int fo = li << 3;
    int e0 = rowptr[node], e1 = rowptr[node + 1];
    int deg = e1 - e0;
    float a0=0.f,a1=0.f,a2=0.f,a3=0.f,a4=0.f,a5=0.f,a6=0.f,a7=0.f;

#define ACC_EDGE(SRC) do { \
        uint4 u = *(const uint4*)&featb[(size_t)(SRC) * F + fo]; \
        a0 += blo(u.x); a1 += bhi(u.x); \
        a2 += blo(u.y); a3 += bhi(u.y); \
        a4 += blo(u.z); a5 += bhi(u.z); \
        a6 += blo(u.w); a7 += bhi(u.w); \
    } while (0)

    int e = e0;
    for (; e + 16 <= e1; e += 16) {
        int s0 = sorted[e + q];
        int s1 = sorted[e + 4 + q];
        int s2 = sorted[e + 8 + q];
        int s3 = sorted[e + 12 + q];
        ACC_EDGE(s0); ACC_EDGE(s1); ACC_EDGE(s2); ACC_EDGE(s3);
    }
    for (; e + 8 <= e1; e += 8) {
        int s0 = sorted[e + q];
        int s1 = sorted[e + 4 + q];
        ACC_EDGE(s0); ACC_EDGE(s1);
    }
    for (; e + 4 <= e1; e += 4) {
        int s0 = sorted[e + q];
        ACC_EDGE(s0);
    }
    if (e < e1 && q < (e1 - e)) {
        int s0 = sorted[e + q];
        ACC_EDGE(s0);
    }
#undef ACC_EDGE

    #pragma unroll
    for (int m = 16; m <= 32; m <<= 1) {
        a0 += __shfl_xor(a0, m); a1 += __shfl_xor(a1, m);
        a2 += __shfl_xor(a2, m); a3 += __shfl_xor(a3, m);
        a4 += __shfl_xor(a4, m); a5 += __shfl_xor(a5, m);
        a6 += __shfl_xor(a6, m); a7 += __shfl_xor(a7, m);
    }

    if (q == 0) {
        float inv = 1.f / (float)(deg > 1 ? deg : 1);
        uint4 o;
        o.x = pk2(a0 * inv, a1 * inv);
        o.y = pk2(a2 * inv, a3 * inv);
        o.z = pk2(a4 * inv, a5 * inv);
        o.w = pk2(a6 * inv, a7 * inv);
        *(uint4*)&aggm[(size_t)node * F + fo] = o;
    }
}

// Persistent MFMA dual GEMM — now 512 threads / 8 waves per block (halves per-wave
// serial chain; 2x epilogue parallelism). Wave w -> 16 cols [w*16, w*16+16), rows 0..31.
// Weights staged ONCE per block (async global_load_lds, linear dest + pre-swizzled src);
// 5 tiles with A double-buffer.
template<int CONV2>
__global__ __launch_bounds__(512) void k_gemm(
    const unsigned short* __restrict__ aggm,
    const unsigned short* __restrict__ selfb,   // conv1: xb, conv2: h1
    const unsigned short* __restrict__ wb,      // wl | wr bf16 [out][k], 64KB
    const float* __restrict__ bias1,
    const float* __restrict__ biasA, const float* __restrict__ biasE,
    const int* __restrict__ rowptr,
    unsigned short* __restrict__ h1, float* __restrict__ stats,
    const float* __restrict__ Wfc, const float* __restrict__ bfc,
    float* __restrict__ out)
{
    __shared__ __align__(16) char smem[SM_TOT];
    int t = threadIdx.x;
    int nb0 = blockIdx.x * (NT * TPB);
    int w = t >> 6, lane = t & 63;
    int li = lane & 15, kg = lane >> 4;
    float (*sC)[132] = (float(*)[132])(smem + SM_C);

    // ---- weight stage (once): 8 async 1KB calls per wave ----
    {
        const char* wsrc = (const char*)wb;
        #pragma unroll
        for (int i = 0; i < 8; ++i) {
            unsigned Lb = (unsigned)(w * 8192 + i * 1024);
            unsigned s = Lb + (unsigned)lane * 16u;
            unsigned g = s ^ (((s >> 8) & 7u) << 4);
            GLL(wsrc + g, smem + Lb);
        }
    }

    // A tile stage: 16 KB over 8 waves (2 x 1KB each); waves 0-3 agg, waves 4-7 self
#define STAGE_A(TI, BUF) { \
        size_t rowb = (size_t)(nb0 + (TI) * NT) * 256u; \
        const char* src_ = (const char*)((w < 4) ? aggm : selfb) + rowb; \
        unsigned sub_ = (unsigned)((w & 3) * 2048); \
        _Pragma("unroll") \
        for (int i_ = 0; i_ < 2; ++i_) { \
            unsigned q_ = sub_ + (unsigned)(i_ * 1024); \
            unsigned s_ = q_ + (unsigned)lane * 16u; \
            unsigned g_ = s_ ^ (((s_ >> 8) & 7u) << 4); \
            GLL(src_ + g_, smem + (BUF) + ((w < 4) ? 0u : 8192u) + q_); \
        } }

    STAGE_A(0, SM_A0)
    __syncthreads();   // vmcnt drained before barrier: weights + tile0 in LDS

    float sAcc = 0.f, s2Acc = 0.f;   // conv1 BN stats, accumulated across tiles
    unsigned swz = ((unsigned)(li & 7) << 4);

    for (int tt = 0; tt < TPB; ++tt) {
        unsigned bufC = (tt & 1) ? SM_A1 : SM_A0;
        unsigned bufN = (tt & 1) ? SM_A0 : SM_A1;
        if (tt + 1 < TPB) STAGE_A(tt + 1, bufN)   // async, lands by next barrier

        int nb = nb0 + tt * NT;

        // ---- MFMA: wave w -> cols [w*16, w*16+16), rows 0..31 ----
        f32x4 acc0 = {0.f,0.f,0.f,0.f}, acc1 = {0.f,0.f,0.f,0.f};
        #pragma unroll
        for (int path = 0; path < 2; ++path) {
            unsigned aBase = bufC + (path ? 8192u : 0u);
            unsigned bBase = path ? 32768u : 0u;
            #pragma unroll
            for (int kc = 0; kc < 4; ++kc) {
                unsigned koff = (unsigned)(kg * 16 + kc * 64);
                bf16x8 a0 = *(const bf16x8*)(smem + aBase + (((unsigned)li * 256u + koff) ^ swz));
                bf16x8 a1 = *(const bf16x8*)(smem + aBase + (((unsigned)(16 + li) * 256u + koff) ^ swz));
                bf16x8 b0 = *(const bf16x8*)(smem + bBase + (((unsigned)(w * 16 + li) * 256u + koff) ^ swz));
                acc0 = __builtin_amdgcn_mfma_f32_16x16x32_bf16(a0, b0, acc0, 0, 0, 0);
                acc1 = __builtin_amdgcn_mfma_f32_16x16x32_bf16(a1, b0, acc1, 0, 0, 0);
            }
        }
        __syncthreads();   // B1: compute-cur done; next-tile async loads drained

        // ---- C -> sC (layout r6/r11-verified: reg r -> row kg*4+r, col li) ----
        #pragma unroll
        for (int r = 0; r < 4; ++r) {
            sC[kg * 4 + r][w * 16 + li]      = acc0[r];
            sC[16 + kg * 4 + r][w * 16 + li] = acc1[r];
        }
        __syncthreads();   // B2

        // ---- bias + row L2 norm: thread -> row t>>4, cols (t&15)*8..+8 ----
        int row = t >> 4, cb = (t & 15) * 8;
        int node = nb + row;
        float v[8];
        float ss = 0.f;
        if constexpr (!CONV2) {
            #pragma unroll
            for (int j = 0; j < 8; ++j) {
                v[j] = sC[row][cb + j] + bias1[cb + j];
                ss = fmaf(v[j], v[j], ss);
            }
        } else {
            float flag = (rowptr[node + 1] > rowptr[node]) ? 1.f : 0.f;
            #pragma unroll
            for (int j = 0; j < 8; ++j) {
                v[j] = sC[row][cb + j] + biasA[cb + j] + flag * biasE[128 + cb + j];
                ss = fmaf(v[j], v[j], ss);
            }
        }
        ss += __shfl_xor(ss, 1); ss += __shfl_xor(ss, 2);
        ss += __shfl_xor(ss, 4); ss += __shfl_xor(ss, 8);
        float sc = 1.f / fmaxf(sqrtf(ss), 1e-12f);

        if constexpr (!CONV2) {
            #pragma unroll
            for (int j = 0; j < 8; ++j) {
                v[j] = fmaxf(v[j] * sc, 0.f);       // normalize then relu
                sC[row][cb + j] = v[j];             // f32 for BN stats
            }
            uint4 p;
            p.x = pk2(v[0], v[1]); p.y = pk2(v[2], v[3]);
            p.z = pk2(v[4], v[5]); p.w = pk2(v[6], v[7]);
            *(uint4*)&h1[(size_t)node * F + cb] = p;
            __syncthreads();   // B3: normalized sC visible for stats
            if (t < F) {
                #pragma unroll
                for (int r = 0; r < NT; ++r) {
                    float h = sC[r][t];
                    sAcc += h; s2Acc = fmaf(h, h, s2Acc);
                }
            }
        } else {
            #pragma unroll
            for (int j = 0; j < 8; ++j) sC[row][cb + j] = v[j] * sc;
            __syncthreads();   // B3: normalized sC visible for fc
            {
                int n = t >> 4, c = t & 15;        // 512 threads = 32 nodes x 16 classes
                float s = bfc[c];
                for (int o = 0; o < F; o += 4) {
                    float4 h4 = *(const float4*)&sC[n][o];
                    float4 w4 = *(const float4*)&Wfc[c * F + o];
                    s += h4.x * w4.x + h4.y * w4.y + h4.z * w4.z + h4.w * w4.w;
                }
                out[(size_t)(nb + n) * NC + c] = s;
            }
        }
        // next iteration's B1 protects sC reuse and buffer swap
    }

    if constexpr (!CONV2) {
        if (t < F) {
            atomicAdd(&stats[t], sAcc);
            atomicAdd(&stats[F + t], s2Acc);
        }
    }
#undef STAGE_A
}

extern "C" void kernel_launch(void* const* d_in, const int* in_sizes, int n_in,
                              void* d_out, int out_size, void* d_ws, size_t ws_size,
                              hipStream_t stream) {
    const float* x     = (const float*)d_in[0];
    const int*   ei    = (const int*)d_in[1];
    const float* W1l   = (const float*)d_in[2];
    const float* b1l   = (const float*)d_in[3];
    const float* W1r   = (const float*)d_in[4];
    const float* gamma = (const float*)d_in[5];
    const float* beta  = (const float*)d_in[6];
    const float* W2l   = (const float*)d_in[7];
    const float* b2l   = (const float*)d_in[8];
    const float* W2r   = (const float*)d_in[9];
    const float* Wfc   = (const float*)d_in[10];
    const float* bfc   = (const float*)d_in[11];

    char* ws = (char*)d_ws;
    int*            rowptr = (int*)(ws + OFF_ROWPTR);
    int*            fill   = (int*)(ws + OFF_FILL);
    int*            bsum   = (int*)(ws + OFF_BSUM);
    int*            sorted = (int*)(ws + OFF_SORTED);
    float*          stats  = (float*)(ws + OFF_STATS);
    unsigned short* w1b    = (unsigned short*)(ws + OFF_W1B);
    unsigned short* w2b    = (unsigned short*)(ws + OFF_W2B);
    unsigned short* xb     = (unsigned short*)(ws + OFF_XB);   // xb then h1 (same rows)
    unsigned short* aggm   = (unsigned short*)(ws + OFF_AGGM);
    float*          biasAE = (float*)(ws + OFF_FILL);          // fill region dead after scatter
    float*          out    = (float*)d_out;

    k_prep<<<NN * F / (256 * 8), 256, 0, stream>>>(x, xb, W1l, W1r, w1b, fill, stats);
    k_hist<<<(NE + 255) / 256, 256, 0, stream>>>(ei, fill);
    k_scan1<<<40, 1024, 0, stream>>>(fill, rowptr, bsum);
    k_scan3<<<40, 1024, 0, stream>>>(rowptr, bsum, fill);
    k_scatter<<<(NE + 255) / 256, 256, 0, stream>>>(ei, fill, sorted);

    // conv1
    k_agg<<<NN / 4, 256, 0, stream>>>(xb, rowptr, sorted, aggm);
    k_gemm<0><<<NN / (NT * TPB), 512, 0, stream>>>(aggm, xb, w1b, b1l, nullptr, nullptr,
                                                   rowptr, xb, stats, nullptr, nullptr, nullptr);
    k_wprep2<<<256, 128, 0, stream>>>(W2l, W2r, b2l, gamma, beta, stats, w2b, biasAE);

    // conv2 (+ fused fc); h1 lives in xb buffer
    k_agg<<<NN / 4, 256, 0, stream>>>(xb, rowptr, sorted, aggm);
    k_gemm<1><<<NN / (NT * TPB), 512, 0, stream>>>(aggm, xb, w2b, nullptr, biasAE, biasAE,
                                                   rowptr, nullptr, nullptr, Wfc, bfc, out);
}